// Round 6
// baseline (1453.088 us; speedup 1.0000x reference)
//
#include <hip/hip_runtime.h>
#include <hip/hip_bf16.h>
#include <cstdint>

#define NFEAT 384
#define DESK 768
#define THIRD 128

typedef __bf16 bf16x8 __attribute__((ext_vector_type(8)));
typedef unsigned short u16x8 __attribute__((ext_vector_type(8)));
typedef unsigned short u16x4 __attribute__((ext_vector_type(4)));
typedef float f32x16 __attribute__((ext_vector_type(16)));
typedef _Float16 h16x2 __attribute__((ext_vector_type(2)));

__device__ __forceinline__ float leaky(float x) { return x > 0.f ? x : 0.01f * x; }

__device__ __forceinline__ unsigned short bfhi(float x) {
  unsigned int u = __float_as_uint(x);
  u += 0x7fffu + ((u >> 16) & 1u);
  return (unsigned short)(u >> 16);
}
__device__ __forceinline__ float bf2f(unsigned short h) {
  return __uint_as_float(((unsigned int)h) << 16);
}
__device__ __forceinline__ void bsplit(float x, unsigned short& h,
                                       unsigned short& l) {
  h = bfhi(x);
  l = bfhi(x - bf2f(h));
}

// LDS bank swizzle: 16B granule (kb,row) -> kb*ROWS + (row ^ (kb<<1)).
__device__ __forceinline__ int swz(int kb, int row, int ROWS) {
  return (kb * ROWS + (row ^ (kb << 1))) * 8;  // short index
}

#define MFMA(a, b, c) __builtin_amdgcn_mfma_f32_32x32x16_bf16(a, b, c, 0, 0, 0)

// ---------------- split-bf16 MFMA GEMM -------------------------------------
// C[M x N] = A[M x K] @ B[K x N], N-tile=128 per by, BM in {64,128}, BK=32.
// 3-set register prefetch issued 3 K-steps ahead. DBUF=1: double-buffered LDS,
// ONE barrier per K-step (6-phase unroll). DBUF=0: single LDS buffer (24KB ->
// more blocks/CU), two barriers per K-step (3-phase unroll). LDS XOR-swizzled.
// EPI 0: leaky(x+bias) -> bf16 hi/lo planes Chi/Clo (row-major, ldc)
// EPI 1: plain -> fp16, PLANE-MAJOR [8][M][48] layout (for sliced agg).
template <int AFP32, int EPI, int BM, int DBUF>
__global__ __launch_bounds__(256, 2) void mfma_gemm(
    const float* __restrict__ Af, const unsigned short* __restrict__ Ahi,
    const unsigned short* __restrict__ Alo,
    const unsigned short* __restrict__ BThi,
    const unsigned short* __restrict__ BTlo, _Float16* __restrict__ Ch16,
    unsigned short* __restrict__ Chi, unsigned short* __restrict__ Clo,
    const float* __restrict__ bias, int M, int K, int ldc) {
  __shared__ unsigned short AhiL[DBUF + 1][4 * BM * 8];
  __shared__ unsigned short AloL[DBUF + 1][4 * BM * 8];
  __shared__ unsigned short BhiL[DBUF + 1][4 * 128 * 8];
  __shared__ unsigned short BloL[DBUF + 1][4 * 128 * 8];
  const int tid = threadIdx.x;
  const int lane = tid & 63;
  const int w = tid >> 6;
  constexpr int MR = BM / 64;
  const int wm = (w >> 1) * (BM / 2);
  const int wn = (w & 1) * 64;
  const int lm = lane & 31, lk = lane >> 5;

  // XCD-aware remap: trio {bn=0,1,2} sharing an A-panel -> ids differing by 8
  int bx = blockIdx.x, by = blockIdx.y;
  if (gridDim.y == 3) {
    int lin = by * gridDim.x + bx;
    int ng = gridDim.x >> 3;
    int full = ng * 24;
    if (lin < full) {
      int g = lin / 24, x = lin - g * 24;
      bx = g * 8 + (x & 7);
      by = x >> 3;
    } else {
      int rem = lin - full;
      int mrem = gridDim.x - (ng << 3);
      bx = (ng << 3) + rem % mrem;
      by = rem / mrem;
    }
  }
  const int m_base = bx * BM, n_base = by * 128;

  f32x16 acc[MR][2];
#pragma unroll
  for (int mi = 0; mi < MR; mi++)
#pragma unroll
    for (int nt = 0; nt < 2; nt++)
#pragma unroll
      for (int r = 0; r < 16; r++) acc[mi][nt][r] = 0.f;

  constexpr int AIT_F = BM / 32;
  constexpr int AIT_H = BM / 64;
  float4 pa[3][AIT_F];
  u16x8 pah[3][AIT_H], pal[3][AIT_H];
  u16x8 pbh[3][2], pbl[3][2];

  auto loadA = [&](int kt, int s) {
    if (AFP32) {
#pragma unroll
      for (int it = 0; it < AIT_F; it++) {
        int r = (tid >> 3) + it * 32;
        int gr = m_base + r;
        float4 av = make_float4(0.f, 0.f, 0.f, 0.f);
        if (gr < M) av = *(const float4*)&Af[(size_t)gr * K + kt + (tid & 7) * 4];
        pa[s][it] = av;
      }
    } else {
#pragma unroll
      for (int it = 0; it < AIT_H; it++) {
        int r = (tid >> 2) + it * 64;
        int gr = m_base + r;
        u16x8 vh = {0, 0, 0, 0, 0, 0, 0, 0};
        u16x8 vl = {0, 0, 0, 0, 0, 0, 0, 0};
        if (gr < M) {
          vh = *(const u16x8*)&Ahi[(size_t)gr * K + kt + (tid & 3) * 8];
          vl = *(const u16x8*)&Alo[(size_t)gr * K + kt + (tid & 3) * 8];
        }
        pah[s][it] = vh;
        pal[s][it] = vl;
      }
    }
  };
  auto loadB = [&](int kt, int s) {
#pragma unroll
    for (int it = 0; it < 2; it++) {
      int n = (tid >> 2) + it * 64;
      pbh[s][it] = *(const u16x8*)&BThi[(size_t)(n_base + n) * K + kt + (tid & 3) * 8];
      pbl[s][it] = *(const u16x8*)&BTlo[(size_t)(n_base + n) * K + kt + (tid & 3) * 8];
    }
  };
  auto storeLDS = [&](int s, int b) {
    if (AFP32) {
#pragma unroll
      for (int it = 0; it < AIT_F; it++) {
        int r = (tid >> 3) + it * 32;
        int q = tid & 7;
        float4 av = pa[s][it];
        unsigned short h0, h1, h2, h3, l0, l1, l2, l3;
        bsplit(av.x, h0, l0);
        bsplit(av.y, h1, l1);
        bsplit(av.z, h2, l2);
        bsplit(av.w, h3, l3);
        int base = swz(q >> 1, r, BM) + (q & 1) * 4;
        u16x4 th;
        th.x = h0; th.y = h1; th.z = h2; th.w = h3;
        u16x4 tl;
        tl.x = l0; tl.y = l1; tl.z = l2; tl.w = l3;
        *(u16x4*)&AhiL[b][base] = th;
        *(u16x4*)&AloL[b][base] = tl;
      }
    } else {
#pragma unroll
      for (int it = 0; it < AIT_H; it++) {
        int r = (tid >> 2) + it * 64;
        int kb = tid & 3;
        *(u16x8*)&AhiL[b][swz(kb, r, BM)] = pah[s][it];
        *(u16x8*)&AloL[b][swz(kb, r, BM)] = pal[s][it];
      }
    }
#pragma unroll
    for (int it = 0; it < 2; it++) {
      int n = (tid >> 2) + it * 64;
      int kb = tid & 3;
      *(u16x8*)&BhiL[b][swz(kb, n, 128)] = pbh[s][it];
      *(u16x8*)&BloL[b][swz(kb, n, 128)] = pbl[s][it];
    }
  };
  auto compute = [&](int b) {
#pragma unroll
    for (int ks = 0; ks < 2; ks++) {
      int kb = 2 * ks + lk;
      bf16x8 ah[MR], al[MR];
#pragma unroll
      for (int mi = 0; mi < MR; mi++) {
        ah[mi] = __builtin_bit_cast(
            bf16x8, *(const u16x8*)&AhiL[b][swz(kb, wm + mi * 32 + lm, BM)]);
        al[mi] = __builtin_bit_cast(
            bf16x8, *(const u16x8*)&AloL[b][swz(kb, wm + mi * 32 + lm, BM)]);
      }
      bf16x8 bh0 = __builtin_bit_cast(
          bf16x8, *(const u16x8*)&BhiL[b][swz(kb, wn + lm, 128)]);
      bf16x8 bh1 = __builtin_bit_cast(
          bf16x8, *(const u16x8*)&BhiL[b][swz(kb, wn + 32 + lm, 128)]);
      bf16x8 bl0 = __builtin_bit_cast(
          bf16x8, *(const u16x8*)&BloL[b][swz(kb, wn + lm, 128)]);
      bf16x8 bl1 = __builtin_bit_cast(
          bf16x8, *(const u16x8*)&BloL[b][swz(kb, wn + 32 + lm, 128)]);
#pragma unroll
      for (int mi = 0; mi < MR; mi++) {
        acc[mi][0] = MFMA(ah[mi], bh0, acc[mi][0]);
        acc[mi][1] = MFMA(ah[mi], bh1, acc[mi][1]);
        acc[mi][0] = MFMA(ah[mi], bl0, acc[mi][0]);
        acc[mi][1] = MFMA(ah[mi], bl1, acc[mi][1]);
        acc[mi][0] = MFMA(al[mi], bh0, acc[mi][0]);
        acc[mi][1] = MFMA(al[mi], bh1, acc[mi][1]);
      }
    }
  };

  const int NK = K >> 5;
  loadA(0, 0);
  loadB(0, 0);
  loadA(32, 1);
  loadB(32, 1);
  loadA(64, 2);
  loadB(64, 2);

  if (DBUF) {
    storeLDS(0, 0);
    __syncthreads();
    for (int m6 = 0; m6 < NK / 6; m6++) {
#pragma unroll
      for (int ph = 0; ph < 6; ph++) {
        const int i = m6 * 6 + ph;
        if (i + 1 < NK) storeLDS((ph + 1) % 3, (ph + 1) & 1);
        if (i + 3 < NK) {
          loadA((i + 3) << 5, ph % 3);
          loadB((i + 3) << 5, ph % 3);
        }
        compute(ph & 1);
        __syncthreads();
      }
    }
  } else {
    for (int m3 = 0; m3 < NK / 3; m3++) {
#pragma unroll
      for (int ph = 0; ph < 3; ph++) {
        const int i = m3 * 3 + ph;
        storeLDS(ph, 0);
        __syncthreads();
        if (i + 3 < NK) {
          loadA((i + 3) << 5, ph);
          loadB((i + 3) << 5, ph);
        }
        compute(0);
        __syncthreads();
      }
    }
  }

  // epilogue: C layout col=lane&31, row=(reg&3)+8*(reg>>2)+4*(lane>>5)
  const int colb = n_base + wn;
#pragma unroll
  for (int mi = 0; mi < MR; mi++) {
#pragma unroll
    for (int nt = 0; nt < 2; nt++) {
      f32x16 v = acc[mi][nt];
      int col = colb + nt * 32 + lm;
      float bv = (EPI == 0) ? bias[col] : 0.f;
      int rb = m_base + wm + mi * 32 + 4 * lk;
      // plane-major base for EPI==1: plane p = col/48, inner c48 = col%48
      int p = col / 48;
      size_t pbase = (size_t)p * M * 48 + (col - p * 48);
#pragma unroll
      for (int rg = 0; rg < 16; rg++) {
        int row = rb + (rg & 3) + 8 * (rg >> 2);
        if (row < M) {
          float x = v[rg];
          if (EPI == 0) {
            x = leaky(x + bv);
            unsigned short h, l;
            bsplit(x, h, l);
            Chi[(size_t)row * ldc + col] = h;
            Clo[(size_t)row * ldc + col] = l;
          } else {
            Ch16[pbase + (size_t)row * 48] = (_Float16)x;
          }
        }
      }
    }
  }
}

// --------- batched split+transpose: src[R][C] f32 -> dst[C][R] bf16 hi/lo ---
__global__ __launch_bounds__(256) void split_transpose_b(
    const float* __restrict__ s0, unsigned short* __restrict__ h0,
    unsigned short* __restrict__ l0, const float* __restrict__ s1,
    unsigned short* __restrict__ h1, unsigned short* __restrict__ l1,
    const float* __restrict__ s2, unsigned short* __restrict__ h2,
    unsigned short* __restrict__ l2) {
  int z = blockIdx.z;
  const float* src = z == 0 ? s0 : (z == 1 ? s1 : s2);
  unsigned short* dsthi = z == 0 ? h0 : (z == 1 ? h1 : h2);
  unsigned short* dstlo = z == 0 ? l0 : (z == 1 ? l1 : l2);
  int R = z == 0 ? 768 : 384;
  int C = z == 0 ? 128 : 384;
  int c0 = blockIdx.x * 32, r0 = blockIdx.y * 32;
  if (c0 >= C || r0 >= R) return;
  __shared__ float tile[32][33];
  int tx = threadIdx.x & 31, ty = threadIdx.x >> 5;
#pragma unroll
  for (int i = 0; i < 4; i++)
    tile[ty + i * 8][tx] = src[(size_t)(r0 + ty + i * 8) * C + c0 + tx];
  __syncthreads();
#pragma unroll
  for (int i = 0; i < 4; i++) {
    int c = c0 + ty + i * 8, r = r0 + tx;
    float v = tile[tx][ty + i * 8];
    unsigned short h, l;
    bsplit(v, h, l);
    dsthi[(size_t)c * R + r] = h;
    dstlo[(size_t)c * R + r] = l;
  }
}

// ---------------- small 384x384x384 GEMM (plain C = A@B, fp32) --------------
__global__ __launch_bounds__(256) void gemm384(const float* __restrict__ A,
                                               const float* __restrict__ B,
                                               float* __restrict__ C) {
  __shared__ float As[16][68];
  __shared__ float Bs[16][64];
  const int tid = threadIdx.x;
  const int mb = blockIdx.x * 64;
  const int nb = blockIdx.y * 64;
  float acc[4][4] = {};
  const int arow = tid >> 2, akq = tid & 3;
  const int brow = tid >> 4, bc4 = tid & 15;
  const int m0 = (tid >> 4) * 4, n0 = (tid & 15) * 4;
  for (int kk = 0; kk < 384; kk += 16) {
    float4 av = *(const float4*)&A[(mb + arow) * 384 + kk + akq * 4];
    As[akq * 4 + 0][arow] = av.x;
    As[akq * 4 + 1][arow] = av.y;
    As[akq * 4 + 2][arow] = av.z;
    As[akq * 4 + 3][arow] = av.w;
    *(float4*)&Bs[brow][bc4 * 4] =
        *(const float4*)&B[(kk + brow) * 384 + nb + bc4 * 4];
    __syncthreads();
#pragma unroll
    for (int k = 0; k < 16; k++) {
      float4 a4 = *(const float4*)&As[k][m0];
      float4 b4 = *(const float4*)&Bs[k][n0];
      float a[4] = {a4.x, a4.y, a4.z, a4.w};
      float b[4] = {b4.x, b4.y, b4.z, b4.w};
#pragma unroll
      for (int i = 0; i < 4; i++)
#pragma unroll
        for (int j = 0; j < 4; j++) acc[i][j] = fmaf(a[i], b[j], acc[i][j]);
    }
    __syncthreads();
  }
#pragma unroll
  for (int i = 0; i < 4; i++)
#pragma unroll
    for (int j = 0; j < 4; j++)
      C[(mb + m0 + i) * 384 + nb + n0 + j] = acc[i][j];
}

// u[j] = sum_k T1[k][j]*b_g1[k] ; v[j] = sum_k W_o1[k][j]*b_g2[k] + b_o1[j]
__global__ void uv_kernel(const float* __restrict__ T1,
                          const float* __restrict__ W_o1,
                          const float* __restrict__ b_g1,
                          const float* __restrict__ b_g2,
                          const float* __restrict__ b_o1, float* __restrict__ u,
                          float* __restrict__ v) {
  int j = blockIdx.x * blockDim.x + threadIdx.x;
  if (j < 384) {
    float su = 0.f, sv = 0.f;
    for (int k = 0; k < 384; k++) {
      su = fmaf(T1[k * 384 + j], b_g1[k], su);
      sv = fmaf(W_o1[k * 384 + j], b_g2[k], sv);
    }
    u[j] = su;
    v[j] = sv + b_o1[j];
  }
}

// num/cat -> x0 plane columns 128..383 (persistent grid-stride over rows)
__global__ __launch_bounds__(256) void numcat_kernel(
    const float* __restrict__ num, const float* __restrict__ cat,
    const float* __restrict__ Wn, const float* __restrict__ bn,
    const float* __restrict__ Wc, const float* __restrict__ bc,
    unsigned short* __restrict__ x0hi, unsigned short* __restrict__ x0lo,
    int N) {
  int c = threadIdx.x;
  for (int i = blockIdx.x; i < N; i += gridDim.x) {
    float val;
    if (c < 128) {
      val = bn[c];
      val = fmaf(num[i * 4 + 0], Wn[0 * 128 + c], val);
      val = fmaf(num[i * 4 + 1], Wn[1 * 128 + c], val);
      val = fmaf(num[i * 4 + 2], Wn[2 * 128 + c], val);
      val = fmaf(num[i * 4 + 3], Wn[3 * 128 + c], val);
    } else {
      int cc = c - 128;
      val = bc[cc];
      val = fmaf(cat[i * 3 + 0], Wc[0 * 128 + cc], val);
      val = fmaf(cat[i * 3 + 1], Wc[1 * 128 + cc], val);
      val = fmaf(cat[i * 3 + 2], Wc[2 * 128 + cc], val);
    }
    val = leaky(val);
    unsigned short h, l;
    bsplit(val, h, l);
    size_t o = (size_t)i * NFEAT + 128 + c;
    x0hi[o] = h;
    x0lo[o] = l;
  }
}

// ---------------- graph prep -----------------------------------------------
__global__ void count_kernel(const int* __restrict__ dst, int* __restrict__ deg,
                             int E) {
  int e = blockIdx.x * blockDim.x + threadIdx.x;
  if (e < E) atomicAdd(&deg[dst[e]], 1);
}

__global__ void scan_reduce(const int* __restrict__ deg,
                            int* __restrict__ partial, int N) {
  __shared__ int sm[512];
  int i = blockIdx.x * 512 + threadIdx.x;
  sm[threadIdx.x] = (i < N) ? deg[i] : 0;
  __syncthreads();
  for (int off = 256; off; off >>= 1) {
    if (threadIdx.x < off) sm[threadIdx.x] += sm[threadIdx.x + off];
    __syncthreads();
  }
  if (threadIdx.x == 0) partial[blockIdx.x] = sm[0];
}

__global__ void scan_top(int* partial, int nb) {
  if (threadIdx.x == 0 && blockIdx.x == 0) {
    int run = 0;
    for (int b = 0; b < nb; b++) {
      int t = partial[b];
      partial[b] = run;
      run += t;
    }
  }
}

// exclusive scan + offsets/cursor + fused dinv
__global__ void scan_down(const int* __restrict__ deg,
                          const int* __restrict__ partial,
                          int* __restrict__ offsets, int* __restrict__ cursor,
                          float* __restrict__ dinv, int N, int E) {
  __shared__ int sm[512];
  int t = threadIdx.x;
  int i = blockIdx.x * 512 + t;
  int val = (i < N) ? deg[i] : 0;
  sm[t] = val;
  __syncthreads();
  for (int off = 1; off < 512; off <<= 1) {
    int add = (t >= off) ? sm[t - off] : 0;
    __syncthreads();
    sm[t] += add;
    __syncthreads();
  }
  if (i < N) {
    int ex = partial[blockIdx.x] + sm[t] - val;
    offsets[i] = ex;
    cursor[i] = ex;
    dinv[i] = 1.0f / sqrtf((float)val + 1.0f);
  }
  if (i == 0) offsets[N] = E;
}

// csr_off stores src*48 (plane-row offset in fp16 elements)
__global__ void fill_kernel(const int* __restrict__ src,
                            const int* __restrict__ dst,
                            int* __restrict__ cursor,
                            int* __restrict__ csr_off,
                            float* __restrict__ csr_w,
                            const float* __restrict__ dinv, int E) {
  int e = blockIdx.x * blockDim.x + threadIdx.x;
  if (e < E) {
    int s = src[e], d = dst[e];
    int slot = atomicAdd(&cursor[d], 1);
    csr_off[slot] = s * 48;
    csr_w[slot] = dinv[s] * dinv[d];
  }
}

// out[i] = b_o2 (bias init; FINAL agg slices atomicAdd their partials)
__global__ void init_out(const float* __restrict__ b_o2,
                         float* __restrict__ out, int N) {
  int i = blockIdx.x * blockDim.x + threadIdx.x;
  if (i < N) {
    out[2 * i + 0] = b_o2[0];
    out[2 * i + 1] = b_o2[1];
  }
}

// ---- XCD-sliced EDGE-PARALLEL aggregation: xout = Ahat @ xin (fp16 planes) -
// xin/xout plane-major [8][N][48]; slice = blockIdx.x % 8 (round-robin ->
// per-XCD 4.8MB gather working set ~fits the private 4MB L2; validated by
// R5's FETCH_SIZE 300->174MB).
// Block = 192 threads = 8 edge-lanes x 24 feature-lanes, ONE row at a time:
// no divergence; csr staged to LDS via coalesced loads (<=64/round, padded to
// x8 with w=0); each thread gathers deg/8 rows at its 4B feature slot (24-lane
// 96B bursts); LDS 8->1 reduce over edge-lanes per row.
// WRITE_S: slice-0 blocks emit s_i. FINAL: per-slice partial W_o2 dot ->
// atomicAdd into bias-initialized out.
template <int WRITE_S, int FINAL>
__global__ __launch_bounds__(192) void agg_ep(
    const _Float16* __restrict__ xin, _Float16* __restrict__ xout,
    const int* __restrict__ offsets, const int* __restrict__ csr_off,
    const float* __restrict__ csr_w, const float* __restrict__ dinv,
    float* __restrict__ sout, const float* __restrict__ svec,
    const float* __restrict__ uvec, const float* __restrict__ vvec,
    const float* __restrict__ W_o2, float* __restrict__ out, int N) {
  const int t = threadIdx.x;
  const int e8 = t / 24;      // 0..7 edge lane
  const int l = t - e8 * 24;  // 0..23 feature lane (2 fp16 each)
  const int slice = blockIdx.x & 7;
  const int sb = blockIdx.x >> 3;
  const int nsb = gridDim.x >> 3;
  const _Float16* xp = xin + (size_t)slice * N * 48;
  _Float16* op = FINAL ? nullptr : xout + (size_t)slice * N * 48;
  __shared__ int ssrc[64];
  __shared__ float sw[64];
  __shared__ float red[8][24][2];
  __shared__ float rw[8];
  __shared__ float rc[24][2];

  float u0 = 0.f, u1 = 0.f, vc0 = 0.f, vc1 = 0.f;
  float w00 = 0.f, w01 = 0.f, w10 = 0.f, w11 = 0.f;
  if (FINAL && t < 24) {
    const int f = slice * 48 + 2 * t;
    u0 = uvec[f];
    u1 = uvec[f + 1];
    vc0 = vvec[f];
    vc1 = vvec[f + 1];
    w00 = W_o2[f * 2 + 0];
    w01 = W_o2[f * 2 + 1];
    w10 = W_o2[(f + 1) * 2 + 0];
    w11 = W_o2[(f + 1) * 2 + 1];
  }

  for (int i = sb; i < N; i += nsb) {
    const int beg = offsets[i];
    const int deg = offsets[i + 1] - beg;
    float ax = 0.f, ay = 0.f, wp = 0.f;
    for (int j0 = 0; j0 < deg; j0 += 64) {
      int cnt = min(64, deg - j0);
      int cntp = (cnt + 7) & ~7;
      if (t < 64) {
        if (t < cnt) {
          ssrc[t] = csr_off[beg + j0 + t];
          sw[t] = csr_w[beg + j0 + t];
        } else {
          ssrc[t] = 0;
          sw[t] = 0.f;
        }
      }
      __syncthreads();
      for (int j = e8; j < cntp; j += 8) {
        float wj = sw[j];
        h16x2 vj = *(const h16x2*)&xp[ssrc[j] + 2 * l];
        ax = fmaf(wj, (float)vj.x, ax);
        ay = fmaf(wj, (float)vj.y, ay);
        if (WRITE_S) wp += wj;
      }
      __syncthreads();
    }
    red[e8][l][0] = ax;
    red[e8][l][1] = ay;
    if (WRITE_S && l == 0) rw[e8] = wp;
    __syncthreads();
    if (t < 24) {
      float di = dinv[i];
      float dii = di * di;
      h16x2 xs = *(const h16x2*)&xp[(size_t)i * 48 + 2 * t];
      float sx = dii * (float)xs.x, sy = dii * (float)xs.y;
#pragma unroll
      for (int k = 0; k < 8; k++) {
        sx += red[k][t][0];
        sy += red[k][t][1];
      }
      if (!FINAL) {
        h16x2 r;
        r.x = (_Float16)sx;
        r.y = (_Float16)sy;
        *(h16x2*)&op[(size_t)i * 48 + 2 * t] = r;
        if (WRITE_S && slice == 0 && t == 0) {
          float wsum = dii;
#pragma unroll
          for (int k = 0; k < 8; k++) wsum += rw[k];
          sout[i] = wsum;
        }
      } else {
        float si = svec[i];
        float q0 = leaky(sx + si * u0 + vc0);
        float q1 = leaky(sy + si * u1 + vc1);
        rc[t][0] = q0 * w00 + q1 * w10;
        rc[t][1] = q0 * w01 + q1 * w11;
      }
    }
    if (FINAL) {
      __syncthreads();
      if (t < 2) {
        float s = 0.f;
#pragma unroll
        for (int k = 0; k < 24; k++) s += rc[k][t];
        atomicAdd(&out[i * 2 + t], s);
      }
      __syncthreads();
    }
  }
}

extern "C" void kernel_launch(void* const* d_in, const int* in_sizes, int n_in,
                              void* d_out, int out_size, void* d_ws,
                              size_t ws_size, hipStream_t stream) {
  const float* des = (const float*)d_in[0];
  // d_in[1] = tweet : unused by the reference
  const float* num_prop = (const float*)d_in[2];
  const float* cat_prop = (const float*)d_in[3];
  const int* edge = (const int*)d_in[4];
  const float* W_des = (const float*)d_in[5];
  const float* b_des = (const float*)d_in[6];
  const float* W_num = (const float*)d_in[7];
  const float* b_num = (const float*)d_in[8];
  const float* W_cat = (const float*)d_in[9];
  const float* b_cat = (const float*)d_in[10];
  const float* W_in = (const float*)d_in[11];
  const float* b_in = (const float*)d_in[12];
  const float* W_g1 = (const float*)d_in[13];
  const float* b_g1 = (const float*)d_in[14];
  const float* W_g2 = (const float*)d_in[15];
  const float* b_g2 = (const float*)d_in[16];
  const float* W_o1 = (const float*)d_in[17];
  const float* b_o1 = (const float*)d_in[18];
  const float* W_o2 = (const float*)d_in[19];
  const float* b_o2 = (const float*)d_in[20];
  float* out = (float*)d_out;

  const int N = in_sizes[0] / DESK;  // 50000
  const int E = in_sizes[4] / 2;     // 800000
  const int* esrc = edge;
  const int* edst = edge + E;

  // workspace layout
  char* ws = (char*)d_ws;
  size_t off = 0;
  auto alloc = [&](size_t n) {
    off = (off + 255) & ~(size_t)255;
    size_t o = off;
    off += n;
    return o;
  };
  float* bufA = (float*)(ws + alloc((size_t)N * NFEAT * 4));  // x0 planes / y
  float* bufB = (float*)(ws + alloc((size_t)N * NFEAT * 4));  // x1 planes / w1
  int* deg = (int*)(ws + alloc((size_t)N * 4));
  int* offsets = (int*)(ws + alloc((size_t)(N + 1) * 4));
  int* cursor = (int*)(ws + alloc((size_t)N * 4));
  int* partial = (int*)(ws + alloc(1024 * 4));
  float* dinv = (float*)(ws + alloc((size_t)N * 4));
  float* svec = (float*)(ws + alloc((size_t)N * 4));
  int* csr_off = (int*)(ws + alloc((size_t)E * 4));
  float* csr_w = (float*)(ws + alloc((size_t)E * 4));
  float* T1 = (float*)(ws + alloc(384 * 384 * 4));
  float* Mmat = (float*)(ws + alloc(384 * 384 * 4));
  float* uvec = (float*)(ws + alloc(384 * 4));
  float* vvec = (float*)(ws + alloc(384 * 4));
  unsigned short* WdThi = (unsigned short*)(ws + alloc(768 * 128 * 2));
  unsigned short* WdTlo = (unsigned short*)(ws + alloc(768 * 128 * 2));
  unsigned short* WiThi = (unsigned short*)(ws + alloc(384 * 384 * 2));
  unsigned short* WiTlo = (unsigned short*)(ws + alloc(384 * 384 * 2));
  unsigned short* MmThi = (unsigned short*)(ws + alloc(384 * 384 * 2));
  unsigned short* MmTlo = (unsigned short*)(ws + alloc(384 * 384 * 2));
  (void)ws_size;
  (void)n_in;
  (void)out_size;

  unsigned short* x0hi = (unsigned short*)bufA;
  unsigned short* x0lo = x0hi + (size_t)N * NFEAT;
  unsigned short* x1hi = (unsigned short*)bufB;
  unsigned short* x1lo = x1hi + (size_t)N * NFEAT;
  _Float16* yb = (_Float16*)bufA;   // plane-major y (overwrites x0 planes)
  _Float16* w1 = (_Float16*)bufB;   // plane-major w1 (overwrites x1 planes)

  hipMemsetAsync(deg, 0, (size_t)N * 4, stream);

  // small precomputes: T1 = W_g2 @ W_o1 ; Mmat = W_g1 @ T1 ; u, v; B^T splits
  dim3 g6(6, 6);
  gemm384<<<g6, 256, 0, stream>>>(W_g2, W_o1, T1);
  gemm384<<<g6, 256, 0, stream>>>(W_g1, T1, Mmat);
  uv_kernel<<<2, 256, 0, stream>>>(T1, W_o1, b_g1, b_g2, b_o1, uvec, vvec);
  split_transpose_b<<<dim3(12, 24, 3), 256, 0, stream>>>(
      W_des, WdThi, WdTlo, W_in, WiThi, WiTlo, Mmat, MmThi, MmTlo);

  const int MT = (N + 127) / 128;    // 391
  const int MT64 = (N + 63) / 64;    // 782
  // x0 cols 0..127 = leaky(des @ W_des + b_des) -> bf16 hi/lo planes
  mfma_gemm<1, 0, 64, 0><<<dim3(MT64, 1), 256, 0, stream>>>(
      des, nullptr, nullptr, WdThi, WdTlo, nullptr, x0hi, x0lo, b_des, N, DESK,
      NFEAT);
  // x0 cols 128..383
  numcat_kernel<<<1024, 256, 0, stream>>>(num_prop, cat_prop, W_num, b_num,
                                          W_cat, b_cat, x0hi, x0lo, N);
  // x1 = leaky(x0 @ W_in + b_in) -> planes
  mfma_gemm<0, 0, 128, 1><<<dim3(MT, 3), 256, 0, stream>>>(
      nullptr, x0hi, x0lo, WiThi, WiTlo, nullptr, x1hi, x1lo, b_in, N, NFEAT,
      NFEAT);
  // y = x1 @ Mmat -> fp16 PLANE-MAJOR (overwrites x0 planes region)
  mfma_gemm<0, 1, 128, 1><<<dim3(MT, 3), 256, 0, stream>>>(
      nullptr, x1hi, x1lo, MmThi, MmTlo, yb, nullptr, nullptr, nullptr, N,
      NFEAT, NFEAT);

  // graph prep
  const int EB = (E + 255) / 256;
  count_kernel<<<EB, 256, 0, stream>>>(edst, deg, E);
  const int NB = (N + 511) / 512;
  scan_reduce<<<NB, 512, 0, stream>>>(deg, partial, N);
  scan_top<<<1, 64, 0, stream>>>(partial, NB);
  scan_down<<<NB, 512, 0, stream>>>(deg, partial, offsets, cursor, dinv, N, E);
  fill_kernel<<<EB, 256, 0, stream>>>(esrc, edst, cursor, csr_off, csr_w, dinv,
                                      E);
  init_out<<<(N + 255) / 256, 256, 0, stream>>>(b_o2, out, N);

  // w1 = Ahat @ y (also s = Ahat @ 1) ; then fused final:
  // out = (leaky(Ahat @ w1 + s*u + v)) @ W_o2 + b_o2
  const int NBS = 512;  // blocks per slice; grid = 8*NBS
  agg_ep<1, 0><<<8 * NBS, 192, 0, stream>>>(
      yb, w1, offsets, csr_off, csr_w, dinv, svec, nullptr, nullptr, nullptr,
      nullptr, nullptr, N);
  agg_ep<0, 1><<<8 * NBS, 192, 0, stream>>>(
      w1, nullptr, offsets, csr_off, csr_w, dinv, nullptr, svec, uvec, vvec,
      W_o2, out, N);
}

// Round 7
// 929.581 us; speedup vs baseline: 1.5632x; 1.5632x over previous
//
#include <hip/hip_runtime.h>
#include <hip/hip_bf16.h>
#include <cstdint>

#define NFEAT 384
#define DESK 768
#define THIRD 128

typedef __bf16 bf16x8 __attribute__((ext_vector_type(8)));
typedef unsigned short u16x8 __attribute__((ext_vector_type(8)));
typedef unsigned short u16x4 __attribute__((ext_vector_type(4)));
typedef float f32x16 __attribute__((ext_vector_type(16)));
typedef _Float16 h16x2 __attribute__((ext_vector_type(2)));

__device__ __forceinline__ float leaky(float x) { return x > 0.f ? x : 0.01f * x; }

__device__ __forceinline__ unsigned short bfhi(float x) {
  unsigned int u = __float_as_uint(x);
  u += 0x7fffu + ((u >> 16) & 1u);
  return (unsigned short)(u >> 16);
}
__device__ __forceinline__ float bf2f(unsigned short h) {
  return __uint_as_float(((unsigned int)h) << 16);
}
__device__ __forceinline__ void bsplit(float x, unsigned short& h,
                                       unsigned short& l) {
  h = bfhi(x);
  l = bfhi(x - bf2f(h));
}

// LDS bank swizzle: 16B granule (kb,row) -> kb*ROWS + (row ^ (kb<<1)).
__device__ __forceinline__ int swz(int kb, int row, int ROWS) {
  return (kb * ROWS + (row ^ (kb << 1))) * 8;  // short index
}

#define MFMA(a, b, c) __builtin_amdgcn_mfma_f32_32x32x16_bf16(a, b, c, 0, 0, 0)

// ---------------- split-bf16 MFMA GEMM -------------------------------------
// C[M x N] = A[M x K] @ B[K x N], N-tile=128 per by, BM in {64,128}, BK=32.
// 3-set register prefetch issued 3 K-steps ahead. DBUF=1: double-buffered LDS,
// ONE barrier per K-step (6-phase unroll). DBUF=0: single LDS buffer (24KB ->
// more blocks/CU), two barriers per K-step (3-phase unroll). LDS XOR-swizzled.
// EPI 0: leaky(x+bias) -> bf16 hi/lo planes Chi/Clo (row-major, ldc)
// EPI 1: plain -> fp16, PLANE-MAJOR [8][M][48] layout (for sliced agg).
template <int AFP32, int EPI, int BM, int DBUF>
__global__ __launch_bounds__(256, 2) void mfma_gemm(
    const float* __restrict__ Af, const unsigned short* __restrict__ Ahi,
    const unsigned short* __restrict__ Alo,
    const unsigned short* __restrict__ BThi,
    const unsigned short* __restrict__ BTlo, _Float16* __restrict__ Ch16,
    unsigned short* __restrict__ Chi, unsigned short* __restrict__ Clo,
    const float* __restrict__ bias, int M, int K, int ldc) {
  __shared__ unsigned short AhiL[DBUF + 1][4 * BM * 8];
  __shared__ unsigned short AloL[DBUF + 1][4 * BM * 8];
  __shared__ unsigned short BhiL[DBUF + 1][4 * 128 * 8];
  __shared__ unsigned short BloL[DBUF + 1][4 * 128 * 8];
  const int tid = threadIdx.x;
  const int lane = tid & 63;
  const int w = tid >> 6;
  constexpr int MR = BM / 64;
  const int wm = (w >> 1) * (BM / 2);
  const int wn = (w & 1) * 64;
  const int lm = lane & 31, lk = lane >> 5;

  // XCD-aware remap: trio {bn=0,1,2} sharing an A-panel -> ids differing by 8
  int bx = blockIdx.x, by = blockIdx.y;
  if (gridDim.y == 3) {
    int lin = by * gridDim.x + bx;
    int ng = gridDim.x >> 3;
    int full = ng * 24;
    if (lin < full) {
      int g = lin / 24, x = lin - g * 24;
      bx = g * 8 + (x & 7);
      by = x >> 3;
    } else {
      int rem = lin - full;
      int mrem = gridDim.x - (ng << 3);
      bx = (ng << 3) + rem % mrem;
      by = rem / mrem;
    }
  }
  const int m_base = bx * BM, n_base = by * 128;

  f32x16 acc[MR][2];
#pragma unroll
  for (int mi = 0; mi < MR; mi++)
#pragma unroll
    for (int nt = 0; nt < 2; nt++)
#pragma unroll
      for (int r = 0; r < 16; r++) acc[mi][nt][r] = 0.f;

  constexpr int AIT_F = BM / 32;
  constexpr int AIT_H = BM / 64;
  float4 pa[3][AIT_F];
  u16x8 pah[3][AIT_H], pal[3][AIT_H];
  u16x8 pbh[3][2], pbl[3][2];

  auto loadA = [&](int kt, int s) {
    if (AFP32) {
#pragma unroll
      for (int it = 0; it < AIT_F; it++) {
        int r = (tid >> 3) + it * 32;
        int gr = m_base + r;
        float4 av = make_float4(0.f, 0.f, 0.f, 0.f);
        if (gr < M) av = *(const float4*)&Af[(size_t)gr * K + kt + (tid & 7) * 4];
        pa[s][it] = av;
      }
    } else {
#pragma unroll
      for (int it = 0; it < AIT_H; it++) {
        int r = (tid >> 2) + it * 64;
        int gr = m_base + r;
        u16x8 vh = {0, 0, 0, 0, 0, 0, 0, 0};
        u16x8 vl = {0, 0, 0, 0, 0, 0, 0, 0};
        if (gr < M) {
          vh = *(const u16x8*)&Ahi[(size_t)gr * K + kt + (tid & 3) * 8];
          vl = *(const u16x8*)&Alo[(size_t)gr * K + kt + (tid & 3) * 8];
        }
        pah[s][it] = vh;
        pal[s][it] = vl;
      }
    }
  };
  auto loadB = [&](int kt, int s) {
#pragma unroll
    for (int it = 0; it < 2; it++) {
      int n = (tid >> 2) + it * 64;
      pbh[s][it] = *(const u16x8*)&BThi[(size_t)(n_base + n) * K + kt + (tid & 3) * 8];
      pbl[s][it] = *(const u16x8*)&BTlo[(size_t)(n_base + n) * K + kt + (tid & 3) * 8];
    }
  };
  auto storeLDS = [&](int s, int b) {
    if (AFP32) {
#pragma unroll
      for (int it = 0; it < AIT_F; it++) {
        int r = (tid >> 3) + it * 32;
        int q = tid & 7;
        float4 av = pa[s][it];
        unsigned short h0, h1, h2, h3, l0, l1, l2, l3;
        bsplit(av.x, h0, l0);
        bsplit(av.y, h1, l1);
        bsplit(av.z, h2, l2);
        bsplit(av.w, h3, l3);
        int base = swz(q >> 1, r, BM) + (q & 1) * 4;
        u16x4 th;
        th.x = h0; th.y = h1; th.z = h2; th.w = h3;
        u16x4 tl;
        tl.x = l0; tl.y = l1; tl.z = l2; tl.w = l3;
        *(u16x4*)&AhiL[b][base] = th;
        *(u16x4*)&AloL[b][base] = tl;
      }
    } else {
#pragma unroll
      for (int it = 0; it < AIT_H; it++) {
        int r = (tid >> 2) + it * 64;
        int kb = tid & 3;
        *(u16x8*)&AhiL[b][swz(kb, r, BM)] = pah[s][it];
        *(u16x8*)&AloL[b][swz(kb, r, BM)] = pal[s][it];
      }
    }
#pragma unroll
    for (int it = 0; it < 2; it++) {
      int n = (tid >> 2) + it * 64;
      int kb = tid & 3;
      *(u16x8*)&BhiL[b][swz(kb, n, 128)] = pbh[s][it];
      *(u16x8*)&BloL[b][swz(kb, n, 128)] = pbl[s][it];
    }
  };
  auto compute = [&](int b) {
#pragma unroll
    for (int ks = 0; ks < 2; ks++) {
      int kb = 2 * ks + lk;
      bf16x8 ah[MR], al[MR];
#pragma unroll
      for (int mi = 0; mi < MR; mi++) {
        ah[mi] = __builtin_bit_cast(
            bf16x8, *(const u16x8*)&AhiL[b][swz(kb, wm + mi * 32 + lm, BM)]);
        al[mi] = __builtin_bit_cast(
            bf16x8, *(const u16x8*)&AloL[b][swz(kb, wm + mi * 32 + lm, BM)]);
      }
      bf16x8 bh0 = __builtin_bit_cast(
          bf16x8, *(const u16x8*)&BhiL[b][swz(kb, wn + lm, 128)]);
      bf16x8 bh1 = __builtin_bit_cast(
          bf16x8, *(const u16x8*)&BhiL[b][swz(kb, wn + 32 + lm, 128)]);
      bf16x8 bl0 = __builtin_bit_cast(
          bf16x8, *(const u16x8*)&BloL[b][swz(kb, wn + lm, 128)]);
      bf16x8 bl1 = __builtin_bit_cast(
          bf16x8, *(const u16x8*)&BloL[b][swz(kb, wn + 32 + lm, 128)]);
#pragma unroll
      for (int mi = 0; mi < MR; mi++) {
        acc[mi][0] = MFMA(ah[mi], bh0, acc[mi][0]);
        acc[mi][1] = MFMA(ah[mi], bh1, acc[mi][1]);
        acc[mi][0] = MFMA(ah[mi], bl0, acc[mi][0]);
        acc[mi][1] = MFMA(ah[mi], bl1, acc[mi][1]);
        acc[mi][0] = MFMA(al[mi], bh0, acc[mi][0]);
        acc[mi][1] = MFMA(al[mi], bh1, acc[mi][1]);
      }
    }
  };

  const int NK = K >> 5;
  loadA(0, 0);
  loadB(0, 0);
  loadA(32, 1);
  loadB(32, 1);
  loadA(64, 2);
  loadB(64, 2);

  if (DBUF) {
    storeLDS(0, 0);
    __syncthreads();
    for (int m6 = 0; m6 < NK / 6; m6++) {
#pragma unroll
      for (int ph = 0; ph < 6; ph++) {
        const int i = m6 * 6 + ph;
        if (i + 1 < NK) storeLDS((ph + 1) % 3, (ph + 1) & 1);
        if (i + 3 < NK) {
          loadA((i + 3) << 5, ph % 3);
          loadB((i + 3) << 5, ph % 3);
        }
        compute(ph & 1);
        __syncthreads();
      }
    }
  } else {
    for (int m3 = 0; m3 < NK / 3; m3++) {
#pragma unroll
      for (int ph = 0; ph < 3; ph++) {
        const int i = m3 * 3 + ph;
        storeLDS(ph, 0);
        __syncthreads();
        if (i + 3 < NK) {
          loadA((i + 3) << 5, ph);
          loadB((i + 3) << 5, ph);
        }
        compute(0);
        __syncthreads();
      }
    }
  }

  // epilogue: C layout col=lane&31, row=(reg&3)+8*(reg>>2)+4*(lane>>5)
  const int colb = n_base + wn;
#pragma unroll
  for (int mi = 0; mi < MR; mi++) {
#pragma unroll
    for (int nt = 0; nt < 2; nt++) {
      f32x16 v = acc[mi][nt];
      int col = colb + nt * 32 + lm;
      float bv = (EPI == 0) ? bias[col] : 0.f;
      int rb = m_base + wm + mi * 32 + 4 * lk;
      // plane-major base for EPI==1: plane p = col/48, inner c48 = col%48
      int p = col / 48;
      size_t pbase = (size_t)p * M * 48 + (col - p * 48);
#pragma unroll
      for (int rg = 0; rg < 16; rg++) {
        int row = rb + (rg & 3) + 8 * (rg >> 2);
        if (row < M) {
          float x = v[rg];
          if (EPI == 0) {
            x = leaky(x + bv);
            unsigned short h, l;
            bsplit(x, h, l);
            Chi[(size_t)row * ldc + col] = h;
            Clo[(size_t)row * ldc + col] = l;
          } else {
            Ch16[pbase + (size_t)row * 48] = (_Float16)x;
          }
        }
      }
    }
  }
}

// --------- batched split+transpose: src[R][C] f32 -> dst[C][R] bf16 hi/lo ---
__global__ __launch_bounds__(256) void split_transpose_b(
    const float* __restrict__ s0, unsigned short* __restrict__ h0,
    unsigned short* __restrict__ l0, const float* __restrict__ s1,
    unsigned short* __restrict__ h1, unsigned short* __restrict__ l1,
    const float* __restrict__ s2, unsigned short* __restrict__ h2,
    unsigned short* __restrict__ l2) {
  int z = blockIdx.z;
  const float* src = z == 0 ? s0 : (z == 1 ? s1 : s2);
  unsigned short* dsthi = z == 0 ? h0 : (z == 1 ? h1 : h2);
  unsigned short* dstlo = z == 0 ? l0 : (z == 1 ? l1 : l2);
  int R = z == 0 ? 768 : 384;
  int C = z == 0 ? 128 : 384;
  int c0 = blockIdx.x * 32, r0 = blockIdx.y * 32;
  if (c0 >= C || r0 >= R) return;
  __shared__ float tile[32][33];
  int tx = threadIdx.x & 31, ty = threadIdx.x >> 5;
#pragma unroll
  for (int i = 0; i < 4; i++)
    tile[ty + i * 8][tx] = src[(size_t)(r0 + ty + i * 8) * C + c0 + tx];
  __syncthreads();
#pragma unroll
  for (int i = 0; i < 4; i++) {
    int c = c0 + ty + i * 8, r = r0 + tx;
    float v = tile[tx][ty + i * 8];
    unsigned short h, l;
    bsplit(v, h, l);
    dsthi[(size_t)c * R + r] = h;
    dstlo[(size_t)c * R + r] = l;
  }
}

// ---------------- small 384x384x384 GEMM (plain C = A@B, fp32) --------------
__global__ __launch_bounds__(256) void gemm384(const float* __restrict__ A,
                                               const float* __restrict__ B,
                                               float* __restrict__ C) {
  __shared__ float As[16][68];
  __shared__ float Bs[16][64];
  const int tid = threadIdx.x;
  const int mb = blockIdx.x * 64;
  const int nb = blockIdx.y * 64;
  float acc[4][4] = {};
  const int arow = tid >> 2, akq = tid & 3;
  const int brow = tid >> 4, bc4 = tid & 15;
  const int m0 = (tid >> 4) * 4, n0 = (tid & 15) * 4;
  for (int kk = 0; kk < 384; kk += 16) {
    float4 av = *(const float4*)&A[(mb + arow) * 384 + kk + akq * 4];
    As[akq * 4 + 0][arow] = av.x;
    As[akq * 4 + 1][arow] = av.y;
    As[akq * 4 + 2][arow] = av.z;
    As[akq * 4 + 3][arow] = av.w;
    *(float4*)&Bs[brow][bc4 * 4] =
        *(const float4*)&B[(kk + brow) * 384 + nb + bc4 * 4];
    __syncthreads();
#pragma unroll
    for (int k = 0; k < 16; k++) {
      float4 a4 = *(const float4*)&As[k][m0];
      float4 b4 = *(const float4*)&Bs[k][n0];
      float a[4] = {a4.x, a4.y, a4.z, a4.w};
      float b[4] = {b4.x, b4.y, b4.z, b4.w};
#pragma unroll
      for (int i = 0; i < 4; i++)
#pragma unroll
        for (int j = 0; j < 4; j++) acc[i][j] = fmaf(a[i], b[j], acc[i][j]);
    }
    __syncthreads();
  }
#pragma unroll
  for (int i = 0; i < 4; i++)
#pragma unroll
    for (int j = 0; j < 4; j++)
      C[(mb + m0 + i) * 384 + nb + n0 + j] = acc[i][j];
}

// u[j] = sum_k T1[k][j]*b_g1[k] ; v[j] = sum_k W_o1[k][j]*b_g2[k] + b_o1[j]
__global__ void uv_kernel(const float* __restrict__ T1,
                          const float* __restrict__ W_o1,
                          const float* __restrict__ b_g1,
                          const float* __restrict__ b_g2,
                          const float* __restrict__ b_o1, float* __restrict__ u,
                          float* __restrict__ v) {
  int j = blockIdx.x * blockDim.x + threadIdx.x;
  if (j < 384) {
    float su = 0.f, sv = 0.f;
    for (int k = 0; k < 384; k++) {
      su = fmaf(T1[k * 384 + j], b_g1[k], su);
      sv = fmaf(W_o1[k * 384 + j], b_g2[k], sv);
    }
    u[j] = su;
    v[j] = sv + b_o1[j];
  }
}

// num/cat -> x0 plane columns 128..383 (persistent grid-stride over rows)
__global__ __launch_bounds__(256) void numcat_kernel(
    const float* __restrict__ num, const float* __restrict__ cat,
    const float* __restrict__ Wn, const float* __restrict__ bn,
    const float* __restrict__ Wc, const float* __restrict__ bc,
    unsigned short* __restrict__ x0hi, unsigned short* __restrict__ x0lo,
    int N) {
  int c = threadIdx.x;
  for (int i = blockIdx.x; i < N; i += gridDim.x) {
    float val;
    if (c < 128) {
      val = bn[c];
      val = fmaf(num[i * 4 + 0], Wn[0 * 128 + c], val);
      val = fmaf(num[i * 4 + 1], Wn[1 * 128 + c], val);
      val = fmaf(num[i * 4 + 2], Wn[2 * 128 + c], val);
      val = fmaf(num[i * 4 + 3], Wn[3 * 128 + c], val);
    } else {
      int cc = c - 128;
      val = bc[cc];
      val = fmaf(cat[i * 3 + 0], Wc[0 * 128 + cc], val);
      val = fmaf(cat[i * 3 + 1], Wc[1 * 128 + cc], val);
      val = fmaf(cat[i * 3 + 2], Wc[2 * 128 + cc], val);
    }
    val = leaky(val);
    unsigned short h, l;
    bsplit(val, h, l);
    size_t o = (size_t)i * NFEAT + 128 + c;
    x0hi[o] = h;
    x0lo[o] = l;
  }
}

// ---------------- graph prep -----------------------------------------------
__global__ void count_kernel(const int* __restrict__ dst, int* __restrict__ deg,
                             int E) {
  int e = blockIdx.x * blockDim.x + threadIdx.x;
  if (e < E) atomicAdd(&deg[dst[e]], 1);
}

__global__ void scan_reduce(const int* __restrict__ deg,
                            int* __restrict__ partial, int N) {
  __shared__ int sm[512];
  int i = blockIdx.x * 512 + threadIdx.x;
  sm[threadIdx.x] = (i < N) ? deg[i] : 0;
  __syncthreads();
  for (int off = 256; off; off >>= 1) {
    if (threadIdx.x < off) sm[threadIdx.x] += sm[threadIdx.x + off];
    __syncthreads();
  }
  if (threadIdx.x == 0) partial[blockIdx.x] = sm[0];
}

__global__ void scan_top(int* partial, int nb) {
  if (threadIdx.x == 0 && blockIdx.x == 0) {
    int run = 0;
    for (int b = 0; b < nb; b++) {
      int t = partial[b];
      partial[b] = run;
      run += t;
    }
  }
}

// exclusive scan + offsets/cursor + fused dinv
__global__ void scan_down(const int* __restrict__ deg,
                          const int* __restrict__ partial,
                          int* __restrict__ offsets, int* __restrict__ cursor,
                          float* __restrict__ dinv, int N, int E) {
  __shared__ int sm[512];
  int t = threadIdx.x;
  int i = blockIdx.x * 512 + t;
  int val = (i < N) ? deg[i] : 0;
  sm[t] = val;
  __syncthreads();
  for (int off = 1; off < 512; off <<= 1) {
    int add = (t >= off) ? sm[t - off] : 0;
    __syncthreads();
    sm[t] += add;
    __syncthreads();
  }
  if (i < N) {
    int ex = partial[blockIdx.x] + sm[t] - val;
    offsets[i] = ex;
    cursor[i] = ex;
    dinv[i] = 1.0f / sqrtf((float)val + 1.0f);
  }
  if (i == 0) offsets[N] = E;
}

// csr_off stores src*48 (plane-row offset in fp16 elements)
__global__ void fill_kernel(const int* __restrict__ src,
                            const int* __restrict__ dst,
                            int* __restrict__ cursor,
                            int* __restrict__ csr_off,
                            float* __restrict__ csr_w,
                            const float* __restrict__ dinv, int E) {
  int e = blockIdx.x * blockDim.x + threadIdx.x;
  if (e < E) {
    int s = src[e], d = dst[e];
    int slot = atomicAdd(&cursor[d], 1);
    csr_off[slot] = s * 48;
    csr_w[slot] = dinv[s] * dinv[d];
  }
}

// out[i] = b_o2 (bias init; FINAL agg slices atomicAdd their partials)
__global__ void init_out(const float* __restrict__ b_o2,
                         float* __restrict__ out, int N) {
  int i = blockIdx.x * blockDim.x + threadIdx.x;
  if (i < N) {
    out[2 * i + 0] = b_o2[0];
    out[2 * i + 1] = b_o2[1];
  }
}

// ---- XCD-sliced TEAM aggregation: xout = Ahat @ xin (fp16 planes) ----------
// xin/xout plane-major [8][N][48]; slice = blockIdx.x % 8 (round-robin
// block->XCD => per-XCD 4.8MB slice ~fits private 4MB L2; R5 validated:
// FETCH 300->174MB).
// Block = 192 = 8 teams x 24 lanes, processing 8 CONSECUTIVE rows/iteration.
// Their CSR edges are contiguous -> ONE cooperative 192-thread stage into LDS
// per <=384-edge window (2 barriers), then each team privately walks its own
// row's sub-range from LDS (block barrier already ordered staging; no
// intra-wave sync needed). Rows are team-owned: accumulators live in team
// registers, no cross-team reduction in the aggregate pass.
// Barrier:work ratio ~= R3's good kernel (3072 lane-gathers / 2 barriers).
// WRITE_S: slice-0 team-lane-0 emits s_i. FINAL: per-team W_o2 partial dot ->
// LDS reduce -> atomicAdd into bias-initialized out.
template <int WRITE_S, int FINAL>
__global__ __launch_bounds__(192) void agg_team(
    const _Float16* __restrict__ xin, _Float16* __restrict__ xout,
    const int* __restrict__ offsets, const int* __restrict__ csr_off,
    const float* __restrict__ csr_w, const float* __restrict__ dinv,
    float* __restrict__ sout, const float* __restrict__ svec,
    const float* __restrict__ uvec, const float* __restrict__ vvec,
    const float* __restrict__ W_o2, float* __restrict__ out, int N) {
  const int t = threadIdx.x;
  const int team = t / 24;     // 0..7
  const int l = t - team * 24; // 0..23  (2 fp16 features each)
  const int slice = blockIdx.x & 7;
  const int sb = blockIdx.x >> 3;
  const int nsb = gridDim.x >> 3;
  const _Float16* xp = xin + (size_t)slice * N * 48;
  _Float16* op = FINAL ? nullptr : xout + (size_t)slice * N * 48;
  __shared__ int ssrc[384];
  __shared__ float sw[384];
  __shared__ float rr[8][25][2];  // +1 pad

  float u0 = 0.f, u1 = 0.f, vc0 = 0.f, vc1 = 0.f;
  float w00 = 0.f, w01 = 0.f, w10 = 0.f, w11 = 0.f;
  if (FINAL) {
    const int f = slice * 48 + 2 * l;
    u0 = uvec[f];
    u1 = uvec[f + 1];
    vc0 = vvec[f];
    vc1 = vvec[f + 1];
    w00 = W_o2[f * 2 + 0];
    w01 = W_o2[f * 2 + 1];
    w10 = W_o2[(f + 1) * 2 + 0];
    w11 = W_o2[(f + 1) * 2 + 1];
  }

  const int ngroups = (N + 7) >> 3;
  for (int g = sb; g < ngroups; g += nsb) {
    const int r0 = g * 8;
    const int row = r0 + team;
    const bool valid = row < N;
    const int gbeg = offsets[r0];
    const int gend = offsets[min(r0 + 8, N)];
    int rbeg = 0, rend = 0;
    float ax = 0.f, ay = 0.f, wp = 0.f;
    if (valid) {
      rbeg = offsets[row];
      rend = offsets[row + 1];
      float di = dinv[row];
      float dii = di * di;
      h16x2 xs = *(const h16x2*)&xp[(size_t)row * 48 + 2 * l];
      ax = dii * (float)xs.x;
      ay = dii * (float)xs.y;
      wp = dii;
    }
    for (int wb = gbeg; wb < gend; wb += 384) {
      const int wcnt = min(384, gend - wb);
      for (int k = t; k < wcnt; k += 192) {
        ssrc[k] = csr_off[wb + k];
        sw[k] = csr_w[wb + k];
      }
      __syncthreads();
      int jb = max(rbeg, wb) - wb;
      int je = min(rend, wb + wcnt) - wb;
      int j = jb;
      for (; j + 4 <= je; j += 4) {
        float wj0 = sw[j + 0], wj1 = sw[j + 1], wj2 = sw[j + 2],
              wj3 = sw[j + 3];
        h16x2 v0 = *(const h16x2*)&xp[ssrc[j + 0] + 2 * l];
        h16x2 v1 = *(const h16x2*)&xp[ssrc[j + 1] + 2 * l];
        h16x2 v2 = *(const h16x2*)&xp[ssrc[j + 2] + 2 * l];
        h16x2 v3 = *(const h16x2*)&xp[ssrc[j + 3] + 2 * l];
        ax = fmaf(wj0, (float)v0.x, ax);
        ay = fmaf(wj0, (float)v0.y, ay);
        ax = fmaf(wj1, (float)v1.x, ax);
        ay = fmaf(wj1, (float)v1.y, ay);
        ax = fmaf(wj2, (float)v2.x, ax);
        ay = fmaf(wj2, (float)v2.y, ay);
        ax = fmaf(wj3, (float)v3.x, ax);
        ay = fmaf(wj3, (float)v3.y, ay);
        if (WRITE_S) wp += (wj0 + wj1) + (wj2 + wj3);
      }
      for (; j < je; j++) {
        float wj = sw[j];
        h16x2 vj = *(const h16x2*)&xp[ssrc[j] + 2 * l];
        ax = fmaf(wj, (float)vj.x, ax);
        ay = fmaf(wj, (float)vj.y, ay);
        if (WRITE_S) wp += wj;
      }
      __syncthreads();
    }
    if (!FINAL) {
      if (valid) {
        h16x2 r;
        r.x = (_Float16)ax;
        r.y = (_Float16)ay;
        *(h16x2*)&op[(size_t)row * 48 + 2 * l] = r;
        if (WRITE_S && slice == 0 && l == 0) sout[row] = wp;
      }
    } else {
      float c0 = 0.f, c1 = 0.f;
      if (valid) {
        float si = svec[row];
        float q0 = leaky(ax + si * u0 + vc0);
        float q1 = leaky(ay + si * u1 + vc1);
        c0 = q0 * w00 + q1 * w10;
        c1 = q0 * w01 + q1 * w11;
      }
      rr[team][l][0] = c0;
      rr[team][l][1] = c1;
      __syncthreads();
      if (t < 16) {
        int tm = t >> 1, c = t & 1;
        int orow = r0 + tm;
        if (orow < N) {
          float s = 0.f;
#pragma unroll
          for (int k = 0; k < 24; k++) s += rr[tm][k][c];
          atomicAdd(&out[orow * 2 + c], s);
        }
      }
      __syncthreads();
    }
  }
}

extern "C" void kernel_launch(void* const* d_in, const int* in_sizes, int n_in,
                              void* d_out, int out_size, void* d_ws,
                              size_t ws_size, hipStream_t stream) {
  const float* des = (const float*)d_in[0];
  // d_in[1] = tweet : unused by the reference
  const float* num_prop = (const float*)d_in[2];
  const float* cat_prop = (const float*)d_in[3];
  const int* edge = (const int*)d_in[4];
  const float* W_des = (const float*)d_in[5];
  const float* b_des = (const float*)d_in[6];
  const float* W_num = (const float*)d_in[7];
  const float* b_num = (const float*)d_in[8];
  const float* W_cat = (const float*)d_in[9];
  const float* b_cat = (const float*)d_in[10];
  const float* W_in = (const float*)d_in[11];
  const float* b_in = (const float*)d_in[12];
  const float* W_g1 = (const float*)d_in[13];
  const float* b_g1 = (const float*)d_in[14];
  const float* W_g2 = (const float*)d_in[15];
  const float* b_g2 = (const float*)d_in[16];
  const float* W_o1 = (const float*)d_in[17];
  const float* b_o1 = (const float*)d_in[18];
  const float* W_o2 = (const float*)d_in[19];
  const float* b_o2 = (const float*)d_in[20];
  float* out = (float*)d_out;

  const int N = in_sizes[0] / DESK;  // 50000
  const int E = in_sizes[4] / 2;     // 800000
  const int* esrc = edge;
  const int* edst = edge + E;

  // workspace layout
  char* ws = (char*)d_ws;
  size_t off = 0;
  auto alloc = [&](size_t n) {
    off = (off + 255) & ~(size_t)255;
    size_t o = off;
    off += n;
    return o;
  };
  float* bufA = (float*)(ws + alloc((size_t)N * NFEAT * 4));  // x0 planes / y
  float* bufB = (float*)(ws + alloc((size_t)N * NFEAT * 4));  // x1 planes / w1
  int* deg = (int*)(ws + alloc((size_t)N * 4));
  int* offsets = (int*)(ws + alloc((size_t)(N + 1) * 4));
  int* cursor = (int*)(ws + alloc((size_t)N * 4));
  int* partial = (int*)(ws + alloc(1024 * 4));
  float* dinv = (float*)(ws + alloc((size_t)N * 4));
  float* svec = (float*)(ws + alloc((size_t)N * 4));
  int* csr_off = (int*)(ws + alloc((size_t)E * 4));
  float* csr_w = (float*)(ws + alloc((size_t)E * 4));
  float* T1 = (float*)(ws + alloc(384 * 384 * 4));
  float* Mmat = (float*)(ws + alloc(384 * 384 * 4));
  float* uvec = (float*)(ws + alloc(384 * 4));
  float* vvec = (float*)(ws + alloc(384 * 4));
  unsigned short* WdThi = (unsigned short*)(ws + alloc(768 * 128 * 2));
  unsigned short* WdTlo = (unsigned short*)(ws + alloc(768 * 128 * 2));
  unsigned short* WiThi = (unsigned short*)(ws + alloc(384 * 384 * 2));
  unsigned short* WiTlo = (unsigned short*)(ws + alloc(384 * 384 * 2));
  unsigned short* MmThi = (unsigned short*)(ws + alloc(384 * 384 * 2));
  unsigned short* MmTlo = (unsigned short*)(ws + alloc(384 * 384 * 2));
  (void)ws_size;
  (void)n_in;
  (void)out_size;

  unsigned short* x0hi = (unsigned short*)bufA;
  unsigned short* x0lo = x0hi + (size_t)N * NFEAT;
  unsigned short* x1hi = (unsigned short*)bufB;
  unsigned short* x1lo = x1hi + (size_t)N * NFEAT;
  _Float16* yb = (_Float16*)bufA;   // plane-major y (overwrites x0 planes)
  _Float16* w1 = (_Float16*)bufB;   // plane-major w1 (overwrites x1 planes)

  hipMemsetAsync(deg, 0, (size_t)N * 4, stream);

  // small precomputes: T1 = W_g2 @ W_o1 ; Mmat = W_g1 @ T1 ; u, v; B^T splits
  dim3 g6(6, 6);
  gemm384<<<g6, 256, 0, stream>>>(W_g2, W_o1, T1);
  gemm384<<<g6, 256, 0, stream>>>(W_g1, T1, Mmat);
  uv_kernel<<<2, 256, 0, stream>>>(T1, W_o1, b_g1, b_g2, b_o1, uvec, vvec);
  split_transpose_b<<<dim3(12, 24, 3), 256, 0, stream>>>(
      W_des, WdThi, WdTlo, W_in, WiThi, WiTlo, Mmat, MmThi, MmTlo);

  const int MT = (N + 127) / 128;    // 391
  const int MT64 = (N + 63) / 64;    // 782
  // x0 cols 0..127 = leaky(des @ W_des + b_des) -> bf16 hi/lo planes
  mfma_gemm<1, 0, 64, 0><<<dim3(MT64, 1), 256, 0, stream>>>(
      des, nullptr, nullptr, WdThi, WdTlo, nullptr, x0hi, x0lo, b_des, N, DESK,
      NFEAT);
  // x0 cols 128..383
  numcat_kernel<<<1024, 256, 0, stream>>>(num_prop, cat_prop, W_num, b_num,
                                          W_cat, b_cat, x0hi, x0lo, N);
  // x1 = leaky(x0 @ W_in + b_in) -> planes
  mfma_gemm<0, 0, 128, 1><<<dim3(MT, 3), 256, 0, stream>>>(
      nullptr, x0hi, x0lo, WiThi, WiTlo, nullptr, x1hi, x1lo, b_in, N, NFEAT,
      NFEAT);
  // y = x1 @ Mmat -> fp16 PLANE-MAJOR (overwrites x0 planes region)
  mfma_gemm<0, 1, 128, 1><<<dim3(MT, 3), 256, 0, stream>>>(
      nullptr, x1hi, x1lo, MmThi, MmTlo, yb, nullptr, nullptr, nullptr, N,
      NFEAT, NFEAT);

  // graph prep
  const int EB = (E + 255) / 256;
  count_kernel<<<EB, 256, 0, stream>>>(edst, deg, E);
  const int NB = (N + 511) / 512;
  scan_reduce<<<NB, 512, 0, stream>>>(deg, partial, N);
  scan_top<<<1, 64, 0, stream>>>(partial, NB);
  scan_down<<<NB, 512, 0, stream>>>(deg, partial, offsets, cursor, dinv, N, E);
  fill_kernel<<<EB, 256, 0, stream>>>(esrc, edst, cursor, csr_off, csr_w, dinv,
                                      E);
  init_out<<<(N + 255) / 256, 256, 0, stream>>>(b_o2, out, N);

  // w1 = Ahat @ y (also s = Ahat @ 1) ; then fused final:
  // out = (leaky(Ahat @ w1 + s*u + v)) @ W_o2 + b_o2
  const int NBS = 512;  // blocks per slice; grid = 8*NBS
  agg_team<1, 0><<<8 * NBS, 192, 0, stream>>>(
      yb, w1, offsets, csr_off, csr_w, dinv, svec, nullptr, nullptr, nullptr,
      nullptr, nullptr, N);
  agg_team<0, 1><<<8 * NBS, 192, 0, stream>>>(
      w1, nullptr, offsets, csr_off, csr_w, dinv, nullptr, svec, uvec, vvec,
      W_o2, out, N);
}

// Round 8
// 909.565 us; speedup vs baseline: 1.5976x; 1.0220x over previous
//
#include <hip/hip_runtime.h>
#include <hip/hip_bf16.h>
#include <cstdint>

#define NFEAT 384
#define DESK 768
#define THIRD 128

typedef __bf16 bf16x8 __attribute__((ext_vector_type(8)));
typedef unsigned short u16x8 __attribute__((ext_vector_type(8)));
typedef unsigned short u16x4 __attribute__((ext_vector_type(4)));
typedef float f32x16 __attribute__((ext_vector_type(16)));
typedef _Float16 h16x2 __attribute__((ext_vector_type(2)));

__device__ __forceinline__ float leaky(float x) { return x > 0.f ? x : 0.01f * x; }

__device__ __forceinline__ unsigned short bfhi(float x) {
  unsigned int u = __float_as_uint(x);
  u += 0x7fffu + ((u >> 16) & 1u);
  return (unsigned short)(u >> 16);
}
__device__ __forceinline__ float bf2f(unsigned short h) {
  return __uint_as_float(((unsigned int)h) << 16);
}
__device__ __forceinline__ void bsplit(float x, unsigned short& h,
                                       unsigned short& l) {
  h = bfhi(x);
  l = bfhi(x - bf2f(h));
}

// LDS bank swizzle: 16B granule (kb,row) -> kb*ROWS + (row ^ (kb<<1)).
// Stores (lanes vary kb at same row) spread across all 8 bank-groups;
// reads (lanes vary row at fixed kb) remain conflict-free.
__device__ __forceinline__ int swz(int kb, int row, int ROWS) {
  return (kb * ROWS + (row ^ (kb << 1))) * 8;  // short index
}

#define MFMA(a, b, c) __builtin_amdgcn_mfma_f32_32x32x16_bf16(a, b, c, 0, 0, 0)

// ---------------- split-bf16 MFMA GEMM -------------------------------------
// C[M x N] = A[M x K] @ B[K x N], N-tile=128 per by, BM in {64,128}, BK=32.
// 3-set register prefetch issued 3 K-steps ahead. DBUF=1: double-buffered LDS,
// ONE barrier per K-step (6-phase unroll; NK % 6 == 0). DBUF=0: single LDS
// buffer (24KB -> 6 blocks/CU), two barriers per K-step (3-phase unroll).
// LDS XOR-swizzled (see swz) to kill 4-way store bank conflicts.
// Grid swizzle for gridDim.y==3: the 3 N-tile blocks sharing one A-panel get
// linear ids differing by 8 -> same XCD -> A-panel read once per XCD L2.
// A: fp32 (AFP32=1, split in staging) or bf16 hi/lo planes.
// B: pre-split transposed planes BT[N][K] (hi/lo bf16).
// EPI 0: leaky(x+bias) -> bf16 hi/lo planes Chi/Clo ; EPI 1: plain -> fp16.
template <int AFP32, int EPI, int BM, int DBUF>
__global__ __launch_bounds__(256, 2) void mfma_gemm(
    const float* __restrict__ Af, const unsigned short* __restrict__ Ahi,
    const unsigned short* __restrict__ Alo,
    const unsigned short* __restrict__ BThi,
    const unsigned short* __restrict__ BTlo, _Float16* __restrict__ Ch16,
    unsigned short* __restrict__ Chi, unsigned short* __restrict__ Clo,
    const float* __restrict__ bias, int M, int K, int ldc) {
  __shared__ unsigned short AhiL[DBUF + 1][4 * BM * 8];
  __shared__ unsigned short AloL[DBUF + 1][4 * BM * 8];
  __shared__ unsigned short BhiL[DBUF + 1][4 * 128 * 8];
  __shared__ unsigned short BloL[DBUF + 1][4 * 128 * 8];
  const int tid = threadIdx.x;
  const int lane = tid & 63;
  const int w = tid >> 6;
  constexpr int MR = BM / 64;  // 32-row sub-tiles per wave
  const int wm = (w >> 1) * (BM / 2);
  const int wn = (w & 1) * 64;
  const int lm = lane & 31, lk = lane >> 5;

  // XCD-aware remap: trio {bn=0,1,2} sharing an A-panel -> ids differing by 8
  int bx = blockIdx.x, by = blockIdx.y;
  if (gridDim.y == 3) {
    int lin = by * gridDim.x + bx;
    int ng = gridDim.x >> 3;
    int full = ng * 24;
    if (lin < full) {
      int g = lin / 24, x = lin - g * 24;
      bx = g * 8 + (x & 7);
      by = x >> 3;
    } else {
      int rem = lin - full;
      int mrem = gridDim.x - (ng << 3);
      bx = (ng << 3) + rem % mrem;
      by = rem / mrem;
    }
  }
  const int m_base = bx * BM, n_base = by * 128;

  f32x16 acc[MR][2];
#pragma unroll
  for (int mi = 0; mi < MR; mi++)
#pragma unroll
    for (int nt = 0; nt < 2; nt++)
#pragma unroll
      for (int r = 0; r < 16; r++) acc[mi][nt][r] = 0.f;

  // 3-deep prefetch register sets
  constexpr int AIT_F = BM / 32;  // float4 loads/thread (AFP32 path)
  constexpr int AIT_H = BM / 64;  // u16x8 loads/thread/plane (plane path)
  float4 pa[3][AIT_F];
  u16x8 pah[3][AIT_H], pal[3][AIT_H];
  u16x8 pbh[3][2], pbl[3][2];

  auto loadA = [&](int kt, int s) {
    if (AFP32) {
#pragma unroll
      for (int it = 0; it < AIT_F; it++) {
        int r = (tid >> 3) + it * 32;
        int gr = m_base + r;
        float4 av = make_float4(0.f, 0.f, 0.f, 0.f);
        if (gr < M) av = *(const float4*)&Af[(size_t)gr * K + kt + (tid & 7) * 4];
        pa[s][it] = av;
      }
    } else {
#pragma unroll
      for (int it = 0; it < AIT_H; it++) {
        int r = (tid >> 2) + it * 64;
        int gr = m_base + r;
        u16x8 vh = {0, 0, 0, 0, 0, 0, 0, 0};
        u16x8 vl = {0, 0, 0, 0, 0, 0, 0, 0};
        if (gr < M) {
          vh = *(const u16x8*)&Ahi[(size_t)gr * K + kt + (tid & 3) * 8];
          vl = *(const u16x8*)&Alo[(size_t)gr * K + kt + (tid & 3) * 8];
        }
        pah[s][it] = vh;
        pal[s][it] = vl;
      }
    }
  };
  auto loadB = [&](int kt, int s) {
#pragma unroll
    for (int it = 0; it < 2; it++) {
      int n = (tid >> 2) + it * 64;
      pbh[s][it] = *(const u16x8*)&BThi[(size_t)(n_base + n) * K + kt + (tid & 3) * 8];
      pbl[s][it] = *(const u16x8*)&BTlo[(size_t)(n_base + n) * K + kt + (tid & 3) * 8];
    }
  };
  auto storeLDS = [&](int s, int b) {
    if (AFP32) {
#pragma unroll
      for (int it = 0; it < AIT_F; it++) {
        int r = (tid >> 3) + it * 32;
        int q = tid & 7;
        float4 av = pa[s][it];
        unsigned short h0, h1, h2, h3, l0, l1, l2, l3;
        bsplit(av.x, h0, l0);
        bsplit(av.y, h1, l1);
        bsplit(av.z, h2, l2);
        bsplit(av.w, h3, l3);
        int base = swz(q >> 1, r, BM) + (q & 1) * 4;
        u16x4 th;
        th.x = h0; th.y = h1; th.z = h2; th.w = h3;
        u16x4 tl;
        tl.x = l0; tl.y = l1; tl.z = l2; tl.w = l3;
        *(u16x4*)&AhiL[b][base] = th;
        *(u16x4*)&AloL[b][base] = tl;
      }
    } else {
#pragma unroll
      for (int it = 0; it < AIT_H; it++) {
        int r = (tid >> 2) + it * 64;
        int kb = tid & 3;
        *(u16x8*)&AhiL[b][swz(kb, r, BM)] = pah[s][it];
        *(u16x8*)&AloL[b][swz(kb, r, BM)] = pal[s][it];
      }
    }
#pragma unroll
    for (int it = 0; it < 2; it++) {
      int n = (tid >> 2) + it * 64;
      int kb = tid & 3;
      *(u16x8*)&BhiL[b][swz(kb, n, 128)] = pbh[s][it];
      *(u16x8*)&BloL[b][swz(kb, n, 128)] = pbl[s][it];
    }
  };
  auto compute = [&](int b) {
#pragma unroll
    for (int ks = 0; ks < 2; ks++) {
      int kb = 2 * ks + lk;
      bf16x8 ah[MR], al[MR];
#pragma unroll
      for (int mi = 0; mi < MR; mi++) {
        ah[mi] = __builtin_bit_cast(
            bf16x8, *(const u16x8*)&AhiL[b][swz(kb, wm + mi * 32 + lm, BM)]);
        al[mi] = __builtin_bit_cast(
            bf16x8, *(const u16x8*)&AloL[b][swz(kb, wm + mi * 32 + lm, BM)]);
      }
      bf16x8 bh0 = __builtin_bit_cast(
          bf16x8, *(const u16x8*)&BhiL[b][swz(kb, wn + lm, 128)]);
      bf16x8 bh1 = __builtin_bit_cast(
          bf16x8, *(const u16x8*)&BhiL[b][swz(kb, wn + 32 + lm, 128)]);
      bf16x8 bl0 = __builtin_bit_cast(
          bf16x8, *(const u16x8*)&BloL[b][swz(kb, wn + lm, 128)]);
      bf16x8 bl1 = __builtin_bit_cast(
          bf16x8, *(const u16x8*)&BloL[b][swz(kb, wn + 32 + lm, 128)]);
#pragma unroll
      for (int mi = 0; mi < MR; mi++) {
        acc[mi][0] = MFMA(ah[mi], bh0, acc[mi][0]);
        acc[mi][1] = MFMA(ah[mi], bh1, acc[mi][1]);
        acc[mi][0] = MFMA(ah[mi], bl0, acc[mi][0]);
        acc[mi][1] = MFMA(ah[mi], bl1, acc[mi][1]);
        acc[mi][0] = MFMA(al[mi], bh0, acc[mi][0]);
        acc[mi][1] = MFMA(al[mi], bh1, acc[mi][1]);
      }
    }
  };

  const int NK = K >> 5;
  // prologue: 3 K-steps of loads in flight
  loadA(0, 0);
  loadB(0, 0);
  loadA(32, 1);
  loadB(32, 1);
  loadA(64, 2);
  loadB(64, 2);

  if (DBUF) {
    // 1 barrier per K-step; step i lives in buf i&1; NK % 6 == 0
    storeLDS(0, 0);
    __syncthreads();
    for (int m6 = 0; m6 < NK / 6; m6++) {
#pragma unroll
      for (int ph = 0; ph < 6; ph++) {
        const int i = m6 * 6 + ph;
        if (i + 1 < NK) storeLDS((ph + 1) % 3, (ph + 1) & 1);
        if (i + 3 < NK) {
          loadA((i + 3) << 5, ph % 3);
          loadB((i + 3) << 5, ph % 3);
        }
        compute(ph & 1);
        __syncthreads();
      }
    }
  } else {
    // single buffer, 2 barriers per K-step; NK % 3 == 0
    for (int m3 = 0; m3 < NK / 3; m3++) {
#pragma unroll
      for (int ph = 0; ph < 3; ph++) {
        const int i = m3 * 3 + ph;
        storeLDS(ph, 0);
        __syncthreads();
        if (i + 3 < NK) {  // refill the set just consumed
          loadA((i + 3) << 5, ph);
          loadB((i + 3) << 5, ph);
        }
        compute(0);
        __syncthreads();
      }
    }
  }

  // epilogue: C layout col=lane&31, row=(reg&3)+8*(reg>>2)+4*(lane>>5)
  const int colb = n_base + wn;
#pragma unroll
  for (int mi = 0; mi < MR; mi++) {
#pragma unroll
    for (int nt = 0; nt < 2; nt++) {
      f32x16 v = acc[mi][nt];
      int col = colb + nt * 32 + lm;
      float bv = (EPI == 0) ? bias[col] : 0.f;
      int rb = m_base + wm + mi * 32 + 4 * lk;
#pragma unroll
      for (int rg = 0; rg < 16; rg++) {
        int row = rb + (rg & 3) + 8 * (rg >> 2);
        if (row < M) {
          float x = v[rg];
          if (EPI == 0) {
            x = leaky(x + bv);
            unsigned short h, l;
            bsplit(x, h, l);
            Chi[(size_t)row * ldc + col] = h;
            Clo[(size_t)row * ldc + col] = l;
          } else {
            Ch16[(size_t)row * ldc + col] = (_Float16)x;
          }
        }
      }
    }
  }
}

// --------- batched split+transpose: src[R][C] f32 -> dst[C][R] bf16 hi/lo ---
// z=0: W_des 768x128 ; z=1: W_in 384x384 ; z=2: Mmat 384x384
__global__ __launch_bounds__(256) void split_transpose_b(
    const float* __restrict__ s0, unsigned short* __restrict__ h0,
    unsigned short* __restrict__ l0, const float* __restrict__ s1,
    unsigned short* __restrict__ h1, unsigned short* __restrict__ l1,
    const float* __restrict__ s2, unsigned short* __restrict__ h2,
    unsigned short* __restrict__ l2) {
  int z = blockIdx.z;
  const float* src = z == 0 ? s0 : (z == 1 ? s1 : s2);
  unsigned short* dsthi = z == 0 ? h0 : (z == 1 ? h1 : h2);
  unsigned short* dstlo = z == 0 ? l0 : (z == 1 ? l1 : l2);
  int R = z == 0 ? 768 : 384;
  int C = z == 0 ? 128 : 384;
  int c0 = blockIdx.x * 32, r0 = blockIdx.y * 32;
  if (c0 >= C || r0 >= R) return;
  __shared__ float tile[32][33];
  int tx = threadIdx.x & 31, ty = threadIdx.x >> 5;
#pragma unroll
  for (int i = 0; i < 4; i++)
    tile[ty + i * 8][tx] = src[(size_t)(r0 + ty + i * 8) * C + c0 + tx];
  __syncthreads();
#pragma unroll
  for (int i = 0; i < 4; i++) {
    int c = c0 + ty + i * 8, r = r0 + tx;
    float v = tile[tx][ty + i * 8];
    unsigned short h, l;
    bsplit(v, h, l);
    dsthi[(size_t)c * R + r] = h;
    dstlo[(size_t)c * R + r] = l;
  }
}

// ---------------- small 384x384x384 GEMM (plain C = A@B, fp32) --------------
__global__ __launch_bounds__(256) void gemm384(const float* __restrict__ A,
                                               const float* __restrict__ B,
                                               float* __restrict__ C) {
  __shared__ float As[16][68];
  __shared__ float Bs[16][64];
  const int tid = threadIdx.x;
  const int mb = blockIdx.x * 64;
  const int nb = blockIdx.y * 64;
  float acc[4][4] = {};
  const int arow = tid >> 2, akq = tid & 3;
  const int brow = tid >> 4, bc4 = tid & 15;
  const int m0 = (tid >> 4) * 4, n0 = (tid & 15) * 4;
  for (int kk = 0; kk < 384; kk += 16) {
    float4 av = *(const float4*)&A[(mb + arow) * 384 + kk + akq * 4];
    As[akq * 4 + 0][arow] = av.x;
    As[akq * 4 + 1][arow] = av.y;
    As[akq * 4 + 2][arow] = av.z;
    As[akq * 4 + 3][arow] = av.w;
    *(float4*)&Bs[brow][bc4 * 4] =
        *(const float4*)&B[(kk + brow) * 384 + nb + bc4 * 4];
    __syncthreads();
#pragma unroll
    for (int k = 0; k < 16; k++) {
      float4 a4 = *(const float4*)&As[k][m0];
      float4 b4 = *(const float4*)&Bs[k][n0];
      float a[4] = {a4.x, a4.y, a4.z, a4.w};
      float b[4] = {b4.x, b4.y, b4.z, b4.w};
#pragma unroll
      for (int i = 0; i < 4; i++)
#pragma unroll
        for (int j = 0; j < 4; j++) acc[i][j] = fmaf(a[i], b[j], acc[i][j]);
    }
    __syncthreads();
  }
#pragma unroll
  for (int i = 0; i < 4; i++)
#pragma unroll
    for (int j = 0; j < 4; j++)
      C[(mb + m0 + i) * 384 + nb + n0 + j] = acc[i][j];
}

// u[j] = sum_k T1[k][j]*b_g1[k] ; v[j] = sum_k W_o1[k][j]*b_g2[k] + b_o1[j]
__global__ void uv_kernel(const float* __restrict__ T1,
                          const float* __restrict__ W_o1,
                          const float* __restrict__ b_g1,
                          const float* __restrict__ b_g2,
                          const float* __restrict__ b_o1, float* __restrict__ u,
                          float* __restrict__ v) {
  int j = blockIdx.x * blockDim.x + threadIdx.x;
  if (j < 384) {
    float su = 0.f, sv = 0.f;
    for (int k = 0; k < 384; k++) {
      su = fmaf(T1[k * 384 + j], b_g1[k], su);
      sv = fmaf(W_o1[k * 384 + j], b_g2[k], sv);
    }
    u[j] = su;
    v[j] = sv + b_o1[j];
  }
}

// num/cat -> x0 plane columns 128..383 (persistent grid-stride over rows)
__global__ __launch_bounds__(256) void numcat_kernel(
    const float* __restrict__ num, const float* __restrict__ cat,
    const float* __restrict__ Wn, const float* __restrict__ bn,
    const float* __restrict__ Wc, const float* __restrict__ bc,
    unsigned short* __restrict__ x0hi, unsigned short* __restrict__ x0lo,
    int N) {
  int c = threadIdx.x;
  for (int i = blockIdx.x; i < N; i += gridDim.x) {
    float val;
    if (c < 128) {
      val = bn[c];
      val = fmaf(num[i * 4 + 0], Wn[0 * 128 + c], val);
      val = fmaf(num[i * 4 + 1], Wn[1 * 128 + c], val);
      val = fmaf(num[i * 4 + 2], Wn[2 * 128 + c], val);
      val = fmaf(num[i * 4 + 3], Wn[3 * 128 + c], val);
    } else {
      int cc = c - 128;
      val = bc[cc];
      val = fmaf(cat[i * 3 + 0], Wc[0 * 128 + cc], val);
      val = fmaf(cat[i * 3 + 1], Wc[1 * 128 + cc], val);
      val = fmaf(cat[i * 3 + 2], Wc[2 * 128 + cc], val);
    }
    val = leaky(val);
    unsigned short h, l;
    bsplit(val, h, l);
    size_t o = (size_t)i * NFEAT + 128 + c;
    x0hi[o] = h;
    x0lo[o] = l;
  }
}

// ---------------- graph prep -----------------------------------------------
__global__ void count_kernel(const int* __restrict__ dst, int* __restrict__ deg,
                             int E) {
  int e = blockIdx.x * blockDim.x + threadIdx.x;
  if (e < E) atomicAdd(&deg[dst[e]], 1);
}

__global__ void scan_reduce(const int* __restrict__ deg,
                            int* __restrict__ partial, int N) {
  __shared__ int sm[512];
  int i = blockIdx.x * 512 + threadIdx.x;
  sm[threadIdx.x] = (i < N) ? deg[i] : 0;
  __syncthreads();
  for (int off = 256; off; off >>= 1) {
    if (threadIdx.x < off) sm[threadIdx.x] += sm[threadIdx.x + off];
    __syncthreads();
  }
  if (threadIdx.x == 0) partial[blockIdx.x] = sm[0];
}

__global__ void scan_top(int* partial, int nb) {
  if (threadIdx.x == 0 && blockIdx.x == 0) {
    int run = 0;
    for (int b = 0; b < nb; b++) {
      int t = partial[b];
      partial[b] = run;
      run += t;
    }
  }
}

// exclusive scan + offsets/cursor + fused dinv
__global__ void scan_down(const int* __restrict__ deg,
                          const int* __restrict__ partial,
                          int* __restrict__ offsets, int* __restrict__ cursor,
                          float* __restrict__ dinv, int N, int E) {
  __shared__ int sm[512];
  int t = threadIdx.x;
  int i = blockIdx.x * 512 + t;
  int val = (i < N) ? deg[i] : 0;
  sm[t] = val;
  __syncthreads();
  for (int off = 1; off < 512; off <<= 1) {
    int add = (t >= off) ? sm[t - off] : 0;
    __syncthreads();
    sm[t] += add;
    __syncthreads();
  }
  if (i < N) {
    int ex = partial[blockIdx.x] + sm[t] - val;
    offsets[i] = ex;
    cursor[i] = ex;
    dinv[i] = 1.0f / sqrtf((float)val + 1.0f);
  }
  if (i == 0) offsets[N] = E;
}

// csr_off stores src*NFEAT (premultiplied row offset, fp16-element units)
__global__ void fill_kernel(const int* __restrict__ src,
                            const int* __restrict__ dst,
                            int* __restrict__ cursor,
                            int* __restrict__ csr_off,
                            float* __restrict__ csr_w,
                            const float* __restrict__ dinv, int E) {
  int e = blockIdx.x * blockDim.x + threadIdx.x;
  if (e < E) {
    int s = src[e], d = dst[e];
    int slot = atomicAdd(&cursor[d], 1);
    csr_off[slot] = s * NFEAT;
    csr_w[slot] = dinv[s] * dinv[d];
  }
}

// ---------------- aggregation: xout = Ahat @ xin (fp16 payload) -------------
// persistent grid-stride over rows; 192 threads, half2 per lane.
// WRITE_S: also s_i = (Ahat @ 1)_i.
// FINAL: leaky(acc + s_i*u + v) -> dot W_o2 -> out[i][0:2]
template <int WRITE_S, int FINAL>
__global__ __launch_bounds__(192) void agg_kernel(
    const _Float16* __restrict__ xin, _Float16* __restrict__ xout,
    const int* __restrict__ offsets, const int* __restrict__ csr_off,
    const float* __restrict__ csr_w, const float* __restrict__ dinv,
    float* __restrict__ sout, const float* __restrict__ svec,
    const float* __restrict__ uvec, const float* __restrict__ vvec,
    const float* __restrict__ W_o2, const float* __restrict__ b_o2,
    float* __restrict__ out, int N) {
  const int t = threadIdx.x;
  const int ff = 2 * t;
  __shared__ int ssrc[192];
  __shared__ float sw[192];
  __shared__ float red[3][2];
  float u0 = 0.f, u1 = 0.f, vc0 = 0.f, vc1 = 0.f;
  float w00 = 0.f, w01 = 0.f, w10 = 0.f, w11 = 0.f, bo0 = 0.f, bo1 = 0.f;
  if (FINAL) {
    u0 = uvec[ff];
    u1 = uvec[ff + 1];
    vc0 = vvec[ff];
    vc1 = vvec[ff + 1];
    w00 = W_o2[ff * 2 + 0];
    w01 = W_o2[ff * 2 + 1];
    w10 = W_o2[(ff + 1) * 2 + 0];
    w11 = W_o2[(ff + 1) * 2 + 1];
    bo0 = b_o2[0];
    bo1 = b_o2[1];
  }
  for (int i = blockIdx.x; i < N; i += gridDim.x) {
    int beg = offsets[i], end = offsets[i + 1];
    float di = dinv[i];
    float dii = di * di;
    h16x2 xs = *(const h16x2*)&xin[(size_t)i * NFEAT + ff];
    float A0x = dii * (float)xs.x, A0y = dii * (float)xs.y;
    float A1x = 0.f, A1y = 0.f, A2x = 0.f, A2y = 0.f, A3x = 0.f, A3y = 0.f;
    float wsum = dii;
    for (int j0 = beg; j0 < end; j0 += 192) {
      int cnt = min(192, end - j0);
      if (t < cnt) {
        ssrc[t] = csr_off[j0 + t];
        sw[t] = csr_w[j0 + t];
      }
      __syncthreads();
      int j = 0;
      for (; j + 8 <= cnt; j += 8) {
        int o0 = ssrc[j + 0], o1 = ssrc[j + 1], o2 = ssrc[j + 2],
            o3 = ssrc[j + 3];
        int o4 = ssrc[j + 4], o5 = ssrc[j + 5], o6 = ssrc[j + 6],
            o7 = ssrc[j + 7];
        float w0 = sw[j + 0], w1 = sw[j + 1], w2 = sw[j + 2], w3 = sw[j + 3];
        float w4 = sw[j + 4], w5 = sw[j + 5], w6 = sw[j + 6], w7 = sw[j + 7];
        h16x2 v0 = *(const h16x2*)&xin[o0 + ff];
        h16x2 v1 = *(const h16x2*)&xin[o1 + ff];
        h16x2 v2 = *(const h16x2*)&xin[o2 + ff];
        h16x2 v3 = *(const h16x2*)&xin[o3 + ff];
        h16x2 v4 = *(const h16x2*)&xin[o4 + ff];
        h16x2 v5 = *(const h16x2*)&xin[o5 + ff];
        h16x2 v6 = *(const h16x2*)&xin[o6 + ff];
        h16x2 v7 = *(const h16x2*)&xin[o7 + ff];
        A0x = fmaf(w0, (float)v0.x, A0x);
        A0y = fmaf(w0, (float)v0.y, A0y);
        A1x = fmaf(w1, (float)v1.x, A1x);
        A1y = fmaf(w1, (float)v1.y, A1y);
        A2x = fmaf(w2, (float)v2.x, A2x);
        A2y = fmaf(w2, (float)v2.y, A2y);
        A3x = fmaf(w3, (float)v3.x, A3x);
        A3y = fmaf(w3, (float)v3.y, A3y);
        A0x = fmaf(w4, (float)v4.x, A0x);
        A0y = fmaf(w4, (float)v4.y, A0y);
        A1x = fmaf(w5, (float)v5.x, A1x);
        A1y = fmaf(w5, (float)v5.y, A1y);
        A2x = fmaf(w6, (float)v6.x, A2x);
        A2y = fmaf(w6, (float)v6.y, A2y);
        A3x = fmaf(w7, (float)v7.x, A3x);
        A3y = fmaf(w7, (float)v7.y, A3y);
        if (WRITE_S) wsum += ((w0 + w1) + (w2 + w3)) + ((w4 + w5) + (w6 + w7));
      }
      for (; j < cnt; j++) {
        float wj = sw[j];
        h16x2 vj = *(const h16x2*)&xin[ssrc[j] + ff];
        A0x = fmaf(wj, (float)vj.x, A0x);
        A0y = fmaf(wj, (float)vj.y, A0y);
        if (WRITE_S) wsum += wj;
      }
      __syncthreads();
    }
    float ax = (A0x + A1x) + (A2x + A3x);
    float ay = (A0y + A1y) + (A2y + A3y);
    if (!FINAL) {
      h16x2 r;
      r.x = (_Float16)ax;
      r.y = (_Float16)ay;
      *(h16x2*)&xout[(size_t)i * NFEAT + ff] = r;
      if (WRITE_S && t == 0) sout[i] = wsum;
    } else {
      float si = svec[i];
      float q0 = leaky(ax + si * u0 + vc0);
      float q1 = leaky(ay + si * u1 + vc1);
      float c0 = q0 * w00 + q1 * w10;
      float c1 = q0 * w01 + q1 * w11;
#pragma unroll
      for (int off2 = 32; off2; off2 >>= 1) {
        c0 += __shfl_down(c0, off2, 64);
        c1 += __shfl_down(c1, off2, 64);
      }
      int wid = t >> 6, lane2 = t & 63;
      if (lane2 == 0) {
        red[wid][0] = c0;
        red[wid][1] = c1;
      }
      __syncthreads();
      if (t == 0) {
        out[i * 2 + 0] = red[0][0] + red[1][0] + red[2][0] + bo0;
        out[i * 2 + 1] = red[0][1] + red[1][1] + red[2][1] + bo1;
      }
    }
  }
}

extern "C" void kernel_launch(void* const* d_in, const int* in_sizes, int n_in,
                              void* d_out, int out_size, void* d_ws,
                              size_t ws_size, hipStream_t stream) {
  const float* des = (const float*)d_in[0];
  // d_in[1] = tweet : unused by the reference
  const float* num_prop = (const float*)d_in[2];
  const float* cat_prop = (const float*)d_in[3];
  const int* edge = (const int*)d_in[4];
  const float* W_des = (const float*)d_in[5];
  const float* b_des = (const float*)d_in[6];
  const float* W_num = (const float*)d_in[7];
  const float* b_num = (const float*)d_in[8];
  const float* W_cat = (const float*)d_in[9];
  const float* b_cat = (const float*)d_in[10];
  const float* W_in = (const float*)d_in[11];
  const float* b_in = (const float*)d_in[12];
  const float* W_g1 = (const float*)d_in[13];
  const float* b_g1 = (const float*)d_in[14];
  const float* W_g2 = (const float*)d_in[15];
  const float* b_g2 = (const float*)d_in[16];
  const float* W_o1 = (const float*)d_in[17];
  const float* b_o1 = (const float*)d_in[18];
  const float* W_o2 = (const float*)d_in[19];
  const float* b_o2 = (const float*)d_in[20];
  float* out = (float*)d_out;

  const int N = in_sizes[0] / DESK;  // 50000
  const int E = in_sizes[4] / 2;     // 800000
  const int* esrc = edge;
  const int* edst = edge + E;

  // workspace layout
  char* ws = (char*)d_ws;
  size_t off = 0;
  auto alloc = [&](size_t n) {
    off = (off + 255) & ~(size_t)255;
    size_t o = off;
    off += n;
    return o;
  };
  float* bufA = (float*)(ws + alloc((size_t)N * NFEAT * 4));  // x0 planes / y
  float* bufB = (float*)(ws + alloc((size_t)N * NFEAT * 4));  // x1 planes / w1
  int* deg = (int*)(ws + alloc((size_t)N * 4));
  int* offsets = (int*)(ws + alloc((size_t)(N + 1) * 4));
  int* cursor = (int*)(ws + alloc((size_t)N * 4));
  int* partial = (int*)(ws + alloc(1024 * 4));
  float* dinv = (float*)(ws + alloc((size_t)N * 4));
  float* svec = (float*)(ws + alloc((size_t)N * 4));
  int* csr_off = (int*)(ws + alloc((size_t)E * 4));
  float* csr_w = (float*)(ws + alloc((size_t)E * 4));
  float* T1 = (float*)(ws + alloc(384 * 384 * 4));
  float* Mmat = (float*)(ws + alloc(384 * 384 * 4));
  float* uvec = (float*)(ws + alloc(384 * 4));
  float* vvec = (float*)(ws + alloc(384 * 4));
  unsigned short* WdThi = (unsigned short*)(ws + alloc(768 * 128 * 2));
  unsigned short* WdTlo = (unsigned short*)(ws + alloc(768 * 128 * 2));
  unsigned short* WiThi = (unsigned short*)(ws + alloc(384 * 384 * 2));
  unsigned short* WiTlo = (unsigned short*)(ws + alloc(384 * 384 * 2));
  unsigned short* MmThi = (unsigned short*)(ws + alloc(384 * 384 * 2));
  unsigned short* MmTlo = (unsigned short*)(ws + alloc(384 * 384 * 2));
  (void)ws_size;
  (void)n_in;
  (void)out_size;

  unsigned short* x0hi = (unsigned short*)bufA;
  unsigned short* x0lo = x0hi + (size_t)N * NFEAT;
  unsigned short* x1hi = (unsigned short*)bufB;
  unsigned short* x1lo = x1hi + (size_t)N * NFEAT;
  _Float16* yb = (_Float16*)bufA;   // overwrites x0 planes after use
  _Float16* w1 = (_Float16*)bufB;   // overwrites x1 planes after use

  hipMemsetAsync(deg, 0, (size_t)N * 4, stream);

  // small precomputes: T1 = W_g2 @ W_o1 ; Mmat = W_g1 @ T1 ; u, v; B^T splits
  dim3 g6(6, 6);
  gemm384<<<g6, 256, 0, stream>>>(W_g2, W_o1, T1);
  gemm384<<<g6, 256, 0, stream>>>(W_g1, T1, Mmat);
  uv_kernel<<<2, 256, 0, stream>>>(T1, W_o1, b_g1, b_g2, b_o1, uvec, vvec);
  split_transpose_b<<<dim3(12, 24, 3), 256, 0, stream>>>(
      W_des, WdThi, WdTlo, W_in, WiThi, WiTlo, Mmat, MmThi, MmTlo);

  const int MT = (N + 127) / 128;    // 391
  const int MT64 = (N + 63) / 64;    // 782
  // x0 cols 0..127 = leaky(des @ W_des + b_des) -> bf16 hi/lo planes
  mfma_gemm<1, 0, 64, 0><<<dim3(MT64, 1), 256, 0, stream>>>(
      des, nullptr, nullptr, WdThi, WdTlo, nullptr, x0hi, x0lo, b_des, N, DESK,
      NFEAT);
  // x0 cols 128..383
  numcat_kernel<<<1024, 256, 0, stream>>>(num_prop, cat_prop, W_num, b_num,
                                          W_cat, b_cat, x0hi, x0lo, N);
  // x1 = leaky(x0 @ W_in + b_in) -> planes
  mfma_gemm<0, 0, 128, 1><<<dim3(MT, 3), 256, 0, stream>>>(
      nullptr, x0hi, x0lo, WiThi, WiTlo, nullptr, x1hi, x1lo, b_in, N, NFEAT,
      NFEAT);
  // y = x1 @ Mmat -> fp16 (overwrites x0 planes region)
  mfma_gemm<0, 1, 128, 1><<<dim3(MT, 3), 256, 0, stream>>>(
      nullptr, x1hi, x1lo, MmThi, MmTlo, yb, nullptr, nullptr, nullptr, N,
      NFEAT, NFEAT);

  // graph prep
  const int EB = (E + 255) / 256;
  count_kernel<<<EB, 256, 0, stream>>>(edst, deg, E);
  const int NB = (N + 511) / 512;
  scan_reduce<<<NB, 512, 0, stream>>>(deg, partial, N);
  scan_top<<<1, 64, 0, stream>>>(partial, NB);
  scan_down<<<NB, 512, 0, stream>>>(deg, partial, offsets, cursor, dinv, N, E);
  fill_kernel<<<EB, 256, 0, stream>>>(esrc, edst, cursor, csr_off, csr_w, dinv,
                                      E);

  // w1 = Ahat @ y (also s = Ahat @ 1) ; then fused final:
  // out = (leaky(Ahat @ w1 + s*u + v)) @ W_o2 + b_o2
  agg_kernel<1, 0><<<4096, 192, 0, stream>>>(
      yb, w1, offsets, csr_off, csr_w, dinv, svec, nullptr, nullptr, nullptr,
      nullptr, nullptr, nullptr, N);
  agg_kernel<0, 1><<<4096, 192, 0, stream>>>(
      w1, nullptr, offsets, csr_off, csr_w, dinv, nullptr, svec, uvec, vvec,
      W_o2, b_o2, out, N);
}

// Round 10
// 901.235 us; speedup vs baseline: 1.6123x; 1.0092x over previous
//
#include <hip/hip_runtime.h>
#include <hip/hip_bf16.h>
#include <cstdint>

#define NFEAT 384
#define DESK 768
#define THIRD 128

typedef __bf16 bf16x8 __attribute__((ext_vector_type(8)));
typedef unsigned short u16x8 __attribute__((ext_vector_type(8)));
typedef unsigned short u16x4 __attribute__((ext_vector_type(4)));
typedef float f32x16 __attribute__((ext_vector_type(16)));
typedef _Float16 h16x2 __attribute__((ext_vector_type(2)));

__device__ __forceinline__ float leaky(float x) { return x > 0.f ? x : 0.01f * x; }

__device__ __forceinline__ unsigned short bfhi(float x) {
  unsigned int u = __float_as_uint(x);
  u += 0x7fffu + ((u >> 16) & 1u);
  return (unsigned short)(u >> 16);
}
__device__ __forceinline__ float bf2f(unsigned short h) {
  return __uint_as_float(((unsigned int)h) << 16);
}
__device__ __forceinline__ void bsplit(float x, unsigned short& h,
                                       unsigned short& l) {
  h = bfhi(x);
  l = bfhi(x - bf2f(h));
}

// LDS bank swizzle: 16B granule (kb,row) -> kb*ROWS + (row ^ (kb<<1)).
// Stores (lanes vary kb at same row) spread across all 8 bank-groups;
// reads (lanes vary row at fixed kb) remain conflict-free.
__device__ __forceinline__ int swz(int kb, int row, int ROWS) {
  return (kb * ROWS + (row ^ (kb << 1))) * 8;  // short index
}

#define MFMA(a, b, c) __builtin_amdgcn_mfma_f32_32x32x16_bf16(a, b, c, 0, 0, 0)

// ---------------- split-bf16 MFMA GEMM -------------------------------------
// C[M x N] = A[M x K] @ B[K x N], N-tile=128 per by, BM in {64,128}, BK=32.
// 3-set register prefetch issued 3 K-steps ahead. DBUF=1: double-buffered LDS,
// ONE barrier per K-step (6-phase unroll; NK % 6 == 0) but 64KB LDS caps at
// 2 blocks/CU. DBUF=0: single LDS buffer (half the LDS -> ~2x blocks/CU),
// two barriers per K-step (3-phase unroll; NK % 3 == 0). These kernels are
// latency-bound: TLP from occupancy beats one fewer barrier (verified on the
// des GEMM R2->R3), so DBUF=0 is the default for all.
// LDS XOR-swizzled (see swz) to kill 4-way store bank conflicts.
// Grid swizzle for gridDim.y==3: the 3 N-tile blocks sharing one A-panel get
// linear ids differing by 8 -> same XCD -> A-panel read once per XCD L2.
// A: fp32 (AFP32=1, split in staging) or bf16 hi/lo planes.
// B: pre-split transposed planes BT[N][K] (hi/lo bf16).
// EPI 0: leaky(x+bias) -> bf16 hi/lo planes Chi/Clo ; EPI 1: plain -> fp16.
template <int AFP32, int EPI, int BM, int DBUF>
__global__ __launch_bounds__(256, 2) void mfma_gemm(
    const float* __restrict__ Af, const unsigned short* __restrict__ Ahi,
    const unsigned short* __restrict__ Alo,
    const unsigned short* __restrict__ BThi,
    const unsigned short* __restrict__ BTlo, _Float16* __restrict__ Ch16,
    unsigned short* __restrict__ Chi, unsigned short* __restrict__ Clo,
    const float* __restrict__ bias, int M, int K, int ldc) {
  __shared__ unsigned short AhiL[DBUF + 1][4 * BM * 8];
  __shared__ unsigned short AloL[DBUF + 1][4 * BM * 8];
  __shared__ unsigned short BhiL[DBUF + 1][4 * 128 * 8];
  __shared__ unsigned short BloL[DBUF + 1][4 * 128 * 8];
  const int tid = threadIdx.x;
  const int lane = tid & 63;
  const int w = tid >> 6;
  constexpr int MR = BM / 64;  // 32-row sub-tiles per wave
  const int wm = (w >> 1) * (BM / 2);
  const int wn = (w & 1) * 64;
  const int lm = lane & 31, lk = lane >> 5;

  // XCD-aware remap: trio {bn=0,1,2} sharing an A-panel -> ids differing by 8
  int bx = blockIdx.x, by = blockIdx.y;
  if (gridDim.y == 3) {
    int lin = by * gridDim.x + bx;
    int ng = gridDim.x >> 3;
    int full = ng * 24;
    if (lin < full) {
      int g = lin / 24, x = lin - g * 24;
      bx = g * 8 + (x & 7);
      by = x >> 3;
    } else {
      int rem = lin - full;
      int mrem = gridDim.x - (ng << 3);
      bx = (ng << 3) + rem % mrem;
      by = rem / mrem;
    }
  }
  const int m_base = bx * BM, n_base = by * 128;

  f32x16 acc[MR][2];
#pragma unroll
  for (int mi = 0; mi < MR; mi++)
#pragma unroll
    for (int nt = 0; nt < 2; nt++)
#pragma unroll
      for (int r = 0; r < 16; r++) acc[mi][nt][r] = 0.f;

  // 3-deep prefetch register sets
  constexpr int AIT_F = BM / 32;  // float4 loads/thread (AFP32 path)
  constexpr int AIT_H = BM / 64;  // u16x8 loads/thread/plane (plane path)
  float4 pa[3][AIT_F];
  u16x8 pah[3][AIT_H], pal[3][AIT_H];
  u16x8 pbh[3][2], pbl[3][2];

  auto loadA = [&](int kt, int s) {
    if (AFP32) {
#pragma unroll
      for (int it = 0; it < AIT_F; it++) {
        int r = (tid >> 3) + it * 32;
        int gr = m_base + r;
        float4 av = make_float4(0.f, 0.f, 0.f, 0.f);
        if (gr < M) av = *(const float4*)&Af[(size_t)gr * K + kt + (tid & 7) * 4];
        pa[s][it] = av;
      }
    } else {
#pragma unroll
      for (int it = 0; it < AIT_H; it++) {
        int r = (tid >> 2) + it * 64;
        int gr = m_base + r;
        u16x8 vh = {0, 0, 0, 0, 0, 0, 0, 0};
        u16x8 vl = {0, 0, 0, 0, 0, 0, 0, 0};
        if (gr < M) {
          vh = *(const u16x8*)&Ahi[(size_t)gr * K + kt + (tid & 3) * 8];
          vl = *(const u16x8*)&Alo[(size_t)gr * K + kt + (tid & 3) * 8];
        }
        pah[s][it] = vh;
        pal[s][it] = vl;
      }
    }
  };
  auto loadB = [&](int kt, int s) {
#pragma unroll
    for (int it = 0; it < 2; it++) {
      int n = (tid >> 2) + it * 64;
      pbh[s][it] = *(const u16x8*)&BThi[(size_t)(n_base + n) * K + kt + (tid & 3) * 8];
      pbl[s][it] = *(const u16x8*)&BTlo[(size_t)(n_base + n) * K + kt + (tid & 3) * 8];
    }
  };
  auto storeLDS = [&](int s, int b) {
    if (AFP32) {
#pragma unroll
      for (int it = 0; it < AIT_F; it++) {
        int r = (tid >> 3) + it * 32;
        int q = tid & 7;
        float4 av = pa[s][it];
        unsigned short h0, h1, h2, h3, l0, l1, l2, l3;
        bsplit(av.x, h0, l0);
        bsplit(av.y, h1, l1);
        bsplit(av.z, h2, l2);
        bsplit(av.w, h3, l3);
        int base = swz(q >> 1, r, BM) + (q & 1) * 4;
        u16x4 th;
        th.x = h0; th.y = h1; th.z = h2; th.w = h3;
        u16x4 tl;
        tl.x = l0; tl.y = l1; tl.z = l2; tl.w = l3;
        *(u16x4*)&AhiL[b][base] = th;
        *(u16x4*)&AloL[b][base] = tl;
      }
    } else {
#pragma unroll
      for (int it = 0; it < AIT_H; it++) {
        int r = (tid >> 2) + it * 64;
        int kb = tid & 3;
        *(u16x8*)&AhiL[b][swz(kb, r, BM)] = pah[s][it];
        *(u16x8*)&AloL[b][swz(kb, r, BM)] = pal[s][it];
      }
    }
#pragma unroll
    for (int it = 0; it < 2; it++) {
      int n = (tid >> 2) + it * 64;
      int kb = tid & 3;
      *(u16x8*)&BhiL[b][swz(kb, n, 128)] = pbh[s][it];
      *(u16x8*)&BloL[b][swz(kb, n, 128)] = pbl[s][it];
    }
  };
  auto compute = [&](int b) {
#pragma unroll
    for (int ks = 0; ks < 2; ks++) {
      int kb = 2 * ks + lk;
      bf16x8 ah[MR], al[MR];
#pragma unroll
      for (int mi = 0; mi < MR; mi++) {
        ah[mi] = __builtin_bit_cast(
            bf16x8, *(const u16x8*)&AhiL[b][swz(kb, wm + mi * 32 + lm, BM)]);
        al[mi] = __builtin_bit_cast(
            bf16x8, *(const u16x8*)&AloL[b][swz(kb, wm + mi * 32 + lm, BM)]);
      }
      bf16x8 bh0 = __builtin_bit_cast(
          bf16x8, *(const u16x8*)&BhiL[b][swz(kb, wn + lm, 128)]);
      bf16x8 bh1 = __builtin_bit_cast(
          bf16x8, *(const u16x8*)&BhiL[b][swz(kb, wn + 32 + lm, 128)]);
      bf16x8 bl0 = __builtin_bit_cast(
          bf16x8, *(const u16x8*)&BloL[b][swz(kb, wn + lm, 128)]);
      bf16x8 bl1 = __builtin_bit_cast(
          bf16x8, *(const u16x8*)&BloL[b][swz(kb, wn + 32 + lm, 128)]);
#pragma unroll
      for (int mi = 0; mi < MR; mi++) {
        acc[mi][0] = MFMA(ah[mi], bh0, acc[mi][0]);
        acc[mi][1] = MFMA(ah[mi], bh1, acc[mi][1]);
        acc[mi][0] = MFMA(ah[mi], bl0, acc[mi][0]);
        acc[mi][1] = MFMA(ah[mi], bl1, acc[mi][1]);
        acc[mi][0] = MFMA(al[mi], bh0, acc[mi][0]);
        acc[mi][1] = MFMA(al[mi], bh1, acc[mi][1]);
      }
    }
  };

  const int NK = K >> 5;
  // prologue: 3 K-steps of loads in flight
  loadA(0, 0);
  loadB(0, 0);
  loadA(32, 1);
  loadB(32, 1);
  loadA(64, 2);
  loadB(64, 2);

  if (DBUF) {
    // 1 barrier per K-step; step i lives in buf i&1; NK % 6 == 0
    storeLDS(0, 0);
    __syncthreads();
    for (int m6 = 0; m6 < NK / 6; m6++) {
#pragma unroll
      for (int ph = 0; ph < 6; ph++) {
        const int i = m6 * 6 + ph;
        if (i + 1 < NK) storeLDS((ph + 1) % 3, (ph + 1) & 1);
        if (i + 3 < NK) {
          loadA((i + 3) << 5, ph % 3);
          loadB((i + 3) << 5, ph % 3);
        }
        compute(ph & 1);
        __syncthreads();
      }
    }
  } else {
    // single buffer, 2 barriers per K-step; NK % 3 == 0
    for (int m3 = 0; m3 < NK / 3; m3++) {
#pragma unroll
      for (int ph = 0; ph < 3; ph++) {
        const int i = m3 * 3 + ph;
        storeLDS(ph, 0);
        __syncthreads();
        if (i + 3 < NK) {  // refill the set just consumed
          loadA((i + 3) << 5, ph);
          loadB((i + 3) << 5, ph);
        }
        compute(0);
        __syncthreads();
      }
    }
  }

  // epilogue: C layout col=lane&31, row=(reg&3)+8*(reg>>2)+4*(lane>>5)
  const int colb = n_base + wn;
#pragma unroll
  for (int mi = 0; mi < MR; mi++) {
#pragma unroll
    for (int nt = 0; nt < 2; nt++) {
      f32x16 v = acc[mi][nt];
      int col = colb + nt * 32 + lm;
      float bv = (EPI == 0) ? bias[col] : 0.f;
      int rb = m_base + wm + mi * 32 + 4 * lk;
#pragma unroll
      for (int rg = 0; rg < 16; rg++) {
        int row = rb + (rg & 3) + 8 * (rg >> 2);
        if (row < M) {
          float x = v[rg];
          if (EPI == 0) {
            x = leaky(x + bv);
            unsigned short h, l;
            bsplit(x, h, l);
            Chi[(size_t)row * ldc + col] = h;
            Clo[(size_t)row * ldc + col] = l;
          } else {
            Ch16[(size_t)row * ldc + col] = (_Float16)x;
          }
        }
      }
    }
  }
}

// --------- batched split+transpose: src[R][C] f32 -> dst[C][R] bf16 hi/lo ---
// z=0: W_des 768x128 ; z=1: W_in 384x384 ; z=2: Mmat 384x384
__global__ __launch_bounds__(256) void split_transpose_b(
    const float* __restrict__ s0, unsigned short* __restrict__ h0,
    unsigned short* __restrict__ l0, const float* __restrict__ s1,
    unsigned short* __restrict__ h1, unsigned short* __restrict__ l1,
    const float* __restrict__ s2, unsigned short* __restrict__ h2,
    unsigned short* __restrict__ l2) {
  int z = blockIdx.z;
  const float* src = z == 0 ? s0 : (z == 1 ? s1 : s2);
  unsigned short* dsthi = z == 0 ? h0 : (z == 1 ? h1 : h2);
  unsigned short* dstlo = z == 0 ? l0 : (z == 1 ? l1 : l2);
  int R = z == 0 ? 768 : 384;
  int C = z == 0 ? 128 : 384;
  int c0 = blockIdx.x * 32, r0 = blockIdx.y * 32;
  if (c0 >= C || r0 >= R) return;
  __shared__ float tile[32][33];
  int tx = threadIdx.x & 31, ty = threadIdx.x >> 5;
#pragma unroll
  for (int i = 0; i < 4; i++)
    tile[ty + i * 8][tx] = src[(size_t)(r0 + ty + i * 8) * C + c0 + tx];
  __syncthreads();
#pragma unroll
  for (int i = 0; i < 4; i++) {
    int c = c0 + ty + i * 8, r = r0 + tx;
    float v = tile[tx][ty + i * 8];
    unsigned short h, l;
    bsplit(v, h, l);
    dsthi[(size_t)c * R + r] = h;
    dstlo[(size_t)c * R + r] = l;
  }
}

// ---------------- small 384x384x384 GEMM (plain C = A@B, fp32) --------------
__global__ __launch_bounds__(256) void gemm384(const float* __restrict__ A,
                                               const float* __restrict__ B,
                                               float* __restrict__ C) {
  __shared__ float As[16][68];
  __shared__ float Bs[16][64];
  const int tid = threadIdx.x;
  const int mb = blockIdx.x * 64;
  const int nb = blockIdx.y * 64;
  float acc[4][4] = {};
  const int arow = tid >> 2, akq = tid & 3;
  const int brow = tid >> 4, bc4 = tid & 15;
  const int m0 = (tid >> 4) * 4, n0 = (tid & 15) * 4;
  for (int kk = 0; kk < 384; kk += 16) {
    float4 av = *(const float4*)&A[(mb + arow) * 384 + kk + akq * 4];
    As[akq * 4 + 0][arow] = av.x;
    As[akq * 4 + 1][arow] = av.y;
    As[akq * 4 + 2][arow] = av.z;
    As[akq * 4 + 3][arow] = av.w;
    *(float4*)&Bs[brow][bc4 * 4] =
        *(const float4*)&B[(kk + brow) * 384 + nb + bc4 * 4];
    __syncthreads();
#pragma unroll
    for (int k = 0; k < 16; k++) {
      float4 a4 = *(const float4*)&As[k][m0];
      float4 b4 = *(const float4*)&Bs[k][n0];
      float a[4] = {a4.x, a4.y, a4.z, a4.w};
      float b[4] = {b4.x, b4.y, b4.z, b4.w};
#pragma unroll
      for (int i = 0; i < 4; i++)
#pragma unroll
        for (int j = 0; j < 4; j++) acc[i][j] = fmaf(a[i], b[j], acc[i][j]);
    }
    __syncthreads();
  }
#pragma unroll
  for (int i = 0; i < 4; i++)
#pragma unroll
    for (int j = 0; j < 4; j++)
      C[(mb + m0 + i) * 384 + nb + n0 + j] = acc[i][j];
}

// u[j] = sum_k T1[k][j]*b_g1[k] ; v[j] = sum_k W_o1[k][j]*b_g2[k] + b_o1[j]
__global__ void uv_kernel(const float* __restrict__ T1,
                          const float* __restrict__ W_o1,
                          const float* __restrict__ b_g1,
                          const float* __restrict__ b_g2,
                          const float* __restrict__ b_o1, float* __restrict__ u,
                          float* __restrict__ v) {
  int j = blockIdx.x * blockDim.x + threadIdx.x;
  if (j < 384) {
    float su = 0.f, sv = 0.f;
    for (int k = 0; k < 384; k++) {
      su = fmaf(T1[k * 384 + j], b_g1[k], su);
      sv = fmaf(W_o1[k * 384 + j], b_g2[k], sv);
    }
    u[j] = su;
    v[j] = sv + b_o1[j];
  }
}

// num/cat -> x0 plane columns 128..383 (persistent grid-stride over rows)
__global__ __launch_bounds__(256) void numcat_kernel(
    const float* __restrict__ num, const float* __restrict__ cat,
    const float* __restrict__ Wn, const float* __restrict__ bn,
    const float* __restrict__ Wc, const float* __restrict__ bc,
    unsigned short* __restrict__ x0hi, unsigned short* __restrict__ x0lo,
    int N) {
  int c = threadIdx.x;
  for (int i = blockIdx.x; i < N; i += gridDim.x) {
    float val;
    if (c < 128) {
      val = bn[c];
      val = fmaf(num[i * 4 + 0], Wn[0 * 128 + c], val);
      val = fmaf(num[i * 4 + 1], Wn[1 * 128 + c], val);
      val = fmaf(num[i * 4 + 2], Wn[2 * 128 + c], val);
      val = fmaf(num[i * 4 + 3], Wn[3 * 128 + c], val);
    } else {
      int cc = c - 128;
      val = bc[cc];
      val = fmaf(cat[i * 3 + 0], Wc[0 * 128 + cc], val);
      val = fmaf(cat[i * 3 + 1], Wc[1 * 128 + cc], val);
      val = fmaf(cat[i * 3 + 2], Wc[2 * 128 + cc], val);
    }
    val = leaky(val);
    unsigned short h, l;
    bsplit(val, h, l);
    size_t o = (size_t)i * NFEAT + 128 + c;
    x0hi[o] = h;
    x0lo[o] = l;
  }
}

// ---------------- graph prep -----------------------------------------------
__global__ void count_kernel(const int* __restrict__ dst, int* __restrict__ deg,
                             int E) {
  int e = blockIdx.x * blockDim.x + threadIdx.x;
  if (e < E) atomicAdd(&deg[dst[e]], 1);
}

__global__ void scan_reduce(const int* __restrict__ deg,
                            int* __restrict__ partial, int N) {
  __shared__ int sm[512];
  int i = blockIdx.x * 512 + threadIdx.x;
  sm[threadIdx.x] = (i < N) ? deg[i] : 0;
  __syncthreads();
  for (int off = 256; off; off >>= 1) {
    if (threadIdx.x < off) sm[threadIdx.x] += sm[threadIdx.x + off];
    __syncthreads();
  }
  if (threadIdx.x == 0) partial[blockIdx.x] = sm[0];
}

__global__ void scan_top(int* partial, int nb) {
  if (threadIdx.x == 0 && blockIdx.x == 0) {
    int run = 0;
    for (int b = 0; b < nb; b++) {
      int t = partial[b];
      partial[b] = run;
      run += t;
    }
  }
}

// exclusive scan + offsets/cursor + fused dinv
__global__ void scan_down(const int* __restrict__ deg,
                          const int* __restrict__ partial,
                          int* __restrict__ offsets, int* __restrict__ cursor,
                          float* __restrict__ dinv, int N, int E) {
  __shared__ int sm[512];
  int t = threadIdx.x;
  int i = blockIdx.x * 512 + t;
  int val = (i < N) ? deg[i] : 0;
  sm[t] = val;
  __syncthreads();
  for (int off = 1; off < 512; off <<= 1) {
    int add = (t >= off) ? sm[t - off] : 0;
    __syncthreads();
    sm[t] += add;
    __syncthreads();
  }
  if (i < N) {
    int ex = partial[blockIdx.x] + sm[t] - val;
    offsets[i] = ex;
    cursor[i] = ex;
    dinv[i] = 1.0f / sqrtf((float)val + 1.0f);
  }
  if (i == 0) offsets[N] = E;
}

// csr_off stores src*NFEAT (premultiplied row offset, fp16-element units)
__global__ void fill_kernel(const int* __restrict__ src,
                            const int* __restrict__ dst,
                            int* __restrict__ cursor,
                            int* __restrict__ csr_off,
                            float* __restrict__ csr_w,
                            const float* __restrict__ dinv, int E) {
  int e = blockIdx.x * blockDim.x + threadIdx.x;
  if (e < E) {
    int s = src[e], d = dst[e];
    int slot = atomicAdd(&cursor[d], 1);
    csr_off[slot] = s * NFEAT;
    csr_w[slot] = dinv[s] * dinv[d];
  }
}

// ---------------- aggregation: xout = Ahat @ xin (fp16 payload) -------------
// persistent grid-stride over rows; 192 threads, half2 per lane.
// WRITE_S: also s_i = (Ahat @ 1)_i.
// FINAL: leaky(acc + s_i*u + v) -> dot W_o2 -> out[i][0:2]
template <int WRITE_S, int FINAL>
__global__ __launch_bounds__(192) void agg_kernel(
    const _Float16* __restrict__ xin, _Float16* __restrict__ xout,
    const int* __restrict__ offsets, const int* __restrict__ csr_off,
    const float* __restrict__ csr_w, const float* __restrict__ dinv,
    float* __restrict__ sout, const float* __restrict__ svec,
    const float* __restrict__ uvec, const float* __restrict__ vvec,
    const float* __restrict__ W_o2, const float* __restrict__ b_o2,
    float* __restrict__ out, int N) {
  const int t = threadIdx.x;
  const int ff = 2 * t;
  __shared__ int ssrc[192];
  __shared__ float sw[192];
  __shared__ float red[3][2];
  float u0 = 0.f, u1 = 0.f, vc0 = 0.f, vc1 = 0.f;
  float w00 = 0.f, w01 = 0.f, w10 = 0.f, w11 = 0.f, bo0 = 0.f, bo1 = 0.f;
  if (FINAL) {
    u0 = uvec[ff];
    u1 = uvec[ff + 1];
    vc0 = vvec[ff];
    vc1 = vvec[ff + 1];
    w00 = W_o2[ff * 2 + 0];
    w01 = W_o2[ff * 2 + 1];
    w10 = W_o2[(ff + 1) * 2 + 0];
    w11 = W_o2[(ff + 1) * 2 + 1];
    bo0 = b_o2[0];
    bo1 = b_o2[1];
  }
  for (int i = blockIdx.x; i < N; i += gridDim.x) {
    int beg = offsets[i], end = offsets[i + 1];
    float di = dinv[i];
    float dii = di * di;
    h16x2 xs = *(const h16x2*)&xin[(size_t)i * NFEAT + ff];
    float A0x = dii * (float)xs.x, A0y = dii * (float)xs.y;
    float A1x = 0.f, A1y = 0.f, A2x = 0.f, A2y = 0.f, A3x = 0.f, A3y = 0.f;
    float wsum = dii;
    for (int j0 = beg; j0 < end; j0 += 192) {
      int cnt = min(192, end - j0);
      if (t < cnt) {
        ssrc[t] = csr_off[j0 + t];
        sw[t] = csr_w[j0 + t];
      }
      __syncthreads();
      int j = 0;
      for (; j + 8 <= cnt; j += 8) {
        int o0 = ssrc[j + 0], o1 = ssrc[j + 1], o2 = ssrc[j + 2],
            o3 = ssrc[j + 3];
        int o4 = ssrc[j + 4], o5 = ssrc[j + 5], o6 = ssrc[j + 6],
            o7 = ssrc[j + 7];
        float w0 = sw[j + 0], w1 = sw[j + 1], w2 = sw[j + 2], w3 = sw[j + 3];
        float w4 = sw[j + 4], w5 = sw[j + 5], w6 = sw[j + 6], w7 = sw[j + 7];
        h16x2 v0 = *(const h16x2*)&xin[o0 + ff];
        h16x2 v1 = *(const h16x2*)&xin[o1 + ff];
        h16x2 v2 = *(const h16x2*)&xin[o2 + ff];
        h16x2 v3 = *(const h16x2*)&xin[o3 + ff];
        h16x2 v4 = *(const h16x2*)&xin[o4 + ff];
        h16x2 v5 = *(const h16x2*)&xin[o5 + ff];
        h16x2 v6 = *(const h16x2*)&xin[o6 + ff];
        h16x2 v7 = *(const h16x2*)&xin[o7 + ff];
        A0x = fmaf(w0, (float)v0.x, A0x);
        A0y = fmaf(w0, (float)v0.y, A0y);
        A1x = fmaf(w1, (float)v1.x, A1x);
        A1y = fmaf(w1, (float)v1.y, A1y);
        A2x = fmaf(w2, (float)v2.x, A2x);
        A2y = fmaf(w2, (float)v2.y, A2y);
        A3x = fmaf(w3, (float)v3.x, A3x);
        A3y = fmaf(w3, (float)v3.y, A3y);
        A0x = fmaf(w4, (float)v4.x, A0x);
        A0y = fmaf(w4, (float)v4.y, A0y);
        A1x = fmaf(w5, (float)v5.x, A1x);
        A1y = fmaf(w5, (float)v5.y, A1y);
        A2x = fmaf(w6, (float)v6.x, A2x);
        A2y = fmaf(w6, (float)v6.y, A2y);
        A3x = fmaf(w7, (float)v7.x, A3x);
        A3y = fmaf(w7, (float)v7.y, A3y);
        if (WRITE_S) wsum += ((w0 + w1) + (w2 + w3)) + ((w4 + w5) + (w6 + w7));
      }
      for (; j < cnt; j++) {
        float wj = sw[j];
        h16x2 vj = *(const h16x2*)&xin[ssrc[j] + ff];
        A0x = fmaf(wj, (float)vj.x, A0x);
        A0y = fmaf(wj, (float)vj.y, A0y);
        if (WRITE_S) wsum += wj;
      }
      __syncthreads();
    }
    float ax = (A0x + A1x) + (A2x + A3x);
    float ay = (A0y + A1y) + (A2y + A3y);
    if (!FINAL) {
      h16x2 r;
      r.x = (_Float16)ax;
      r.y = (_Float16)ay;
      *(h16x2*)&xout[(size_t)i * NFEAT + ff] = r;
      if (WRITE_S && t == 0) sout[i] = wsum;
    } else {
      float si = svec[i];
      float q0 = leaky(ax + si * u0 + vc0);
      float q1 = leaky(ay + si * u1 + vc1);
      float c0 = q0 * w00 + q1 * w10;
      float c1 = q0 * w01 + q1 * w11;
#pragma unroll
      for (int off2 = 32; off2; off2 >>= 1) {
        c0 += __shfl_down(c0, off2, 64);
        c1 += __shfl_down(c1, off2, 64);
      }
      int wid = t >> 6, lane2 = t & 63;
      if (lane2 == 0) {
        red[wid][0] = c0;
        red[wid][1] = c1;
      }
      __syncthreads();
      if (t == 0) {
        out[i * 2 + 0] = red[0][0] + red[1][0] + red[2][0] + bo0;
        out[i * 2 + 1] = red[0][1] + red[1][1] + red[2][1] + bo1;
      }
    }
  }
}

extern "C" void kernel_launch(void* const* d_in, const int* in_sizes, int n_in,
                              void* d_out, int out_size, void* d_ws,
                              size_t ws_size, hipStream_t stream) {
  const float* des = (const float*)d_in[0];
  // d_in[1] = tweet : unused by the reference
  const float* num_prop = (const float*)d_in[2];
  const float* cat_prop = (const float*)d_in[3];
  const int* edge = (const int*)d_in[4];
  const float* W_des = (const float*)d_in[5];
  const float* b_des = (const float*)d_in[6];
  const float* W_num = (const float*)d_in[7];
  const float* b_num = (const float*)d_in[8];
  const float* W_cat = (const float*)d_in[9];
  const float* b_cat = (const float*)d_in[10];
  const float* W_in = (const float*)d_in[11];
  const float* b_in = (const float*)d_in[12];
  const float* W_g1 = (const float*)d_in[13];
  const float* b_g1 = (const float*)d_in[14];
  const float* W_g2 = (const float*)d_in[15];
  const float* b_g2 = (const float*)d_in[16];
  const float* W_o1 = (const float*)d_in[17];
  const float* b_o1 = (const float*)d_in[18];
  const float* W_o2 = (const float*)d_in[19];
  const float* b_o2 = (const float*)d_in[20];
  float* out = (float*)d_out;

  const int N = in_sizes[0] / DESK;  // 50000
  const int E = in_sizes[4] / 2;     // 800000
  const int* esrc = edge;
  const int* edst = edge + E;

  // workspace layout
  char* ws = (char*)d_ws;
  size_t off = 0;
  auto alloc = [&](size_t n) {
    off = (off + 255) & ~(size_t)255;
    size_t o = off;
    off += n;
    return o;
  };
  float* bufA = (float*)(ws + alloc((size_t)N * NFEAT * 4));  // x0 planes / y
  float* bufB = (float*)(ws + alloc((size_t)N * NFEAT * 4));  // x1 planes / w1
  int* deg = (int*)(ws + alloc((size_t)N * 4));
  int* offsets = (int*)(ws + alloc((size_t)(N + 1) * 4));
  int* cursor = (int*)(ws + alloc((size_t)N * 4));
  int* partial = (int*)(ws + alloc(1024 * 4));
  float* dinv = (float*)(ws + alloc((size_t)N * 4));
  float* svec = (float*)(ws + alloc((size_t)N * 4));
  int* csr_off = (int*)(ws + alloc((size_t)E * 4));
  float* csr_w = (float*)(ws + alloc((size_t)E * 4));
  float* T1 = (float*)(ws + alloc(384 * 384 * 4));
  float* Mmat = (float*)(ws + alloc(384 * 384 * 4));
  float* uvec = (float*)(ws + alloc(384 * 4));
  float* vvec = (float*)(ws + alloc(384 * 4));
  unsigned short* WdThi = (unsigned short*)(ws + alloc(768 * 128 * 2));
  unsigned short* WdTlo = (unsigned short*)(ws + alloc(768 * 128 * 2));
  unsigned short* WiThi = (unsigned short*)(ws + alloc(384 * 384 * 2));
  unsigned short* WiTlo = (unsigned short*)(ws + alloc(384 * 384 * 2));
  unsigned short* MmThi = (unsigned short*)(ws + alloc(384 * 384 * 2));
  unsigned short* MmTlo = (unsigned short*)(ws + alloc(384 * 384 * 2));
  (void)ws_size;
  (void)n_in;
  (void)out_size;

  unsigned short* x0hi = (unsigned short*)bufA;
  unsigned short* x0lo = x0hi + (size_t)N * NFEAT;
  unsigned short* x1hi = (unsigned short*)bufB;
  unsigned short* x1lo = x1hi + (size_t)N * NFEAT;
  _Float16* yb = (_Float16*)bufA;   // overwrites x0 planes after use
  _Float16* w1 = (_Float16*)bufB;   // overwrites x1 planes after use

  hipMemsetAsync(deg, 0, (size_t)N * 4, stream);

  // small precomputes: T1 = W_g2 @ W_o1 ; Mmat = W_g1 @ T1 ; u, v; B^T splits
  dim3 g6(6, 6);
  gemm384<<<g6, 256, 0, stream>>>(W_g2, W_o1, T1);
  gemm384<<<g6, 256, 0, stream>>>(W_g1, T1, Mmat);
  uv_kernel<<<2, 256, 0, stream>>>(T1, W_o1, b_g1, b_g2, b_o1, uvec, vvec);
  split_transpose_b<<<dim3(12, 24, 3), 256, 0, stream>>>(
      W_des, WdThi, WdTlo, W_in, WiThi, WiTlo, Mmat, MmThi, MmTlo);

  const int MT = (N + 127) / 128;    // 391
  const int MT64 = (N + 63) / 64;    // 782
  // x0 cols 0..127 = leaky(des @ W_des + b_des) -> bf16 hi/lo planes
  mfma_gemm<1, 0, 64, 0><<<dim3(MT64, 1), 256, 0, stream>>>(
      des, nullptr, nullptr, WdThi, WdTlo, nullptr, x0hi, x0lo, b_des, N, DESK,
      NFEAT);
  // x0 cols 128..383
  numcat_kernel<<<1024, 256, 0, stream>>>(num_prop, cat_prop, W_num, b_num,
                                          W_cat, b_cat, x0hi, x0lo, N);
  // x1 = leaky(x0 @ W_in + b_in) -> planes  (DBUF=0: 32KB LDS, ~2x blocks/CU)
  mfma_gemm<0, 0, 128, 0><<<dim3(MT, 3), 256, 0, stream>>>(
      nullptr, x0hi, x0lo, WiThi, WiTlo, nullptr, x1hi, x1lo, b_in, N, NFEAT,
      NFEAT);
  // y = x1 @ Mmat -> fp16 (overwrites x0 planes region)  (DBUF=0)
  mfma_gemm<0, 1, 128, 0><<<dim3(MT, 3), 256, 0, stream>>>(
      nullptr, x1hi, x1lo, MmThi, MmTlo, yb, nullptr, nullptr, nullptr, N,
      NFEAT, NFEAT);

  // graph prep
  const int EB = (E + 255) / 256;
  count_kernel<<<EB, 256, 0, stream>>>(edst, deg, E);
  const int NB = (N + 511) / 512;
  scan_reduce<<<NB, 512, 0, stream>>>(deg, partial, N);
  scan_top<<<1, 64, 0, stream>>>(partial, NB);
  scan_down<<<NB, 512, 0, stream>>>(deg, partial, offsets, cursor, dinv, N, E);
  fill_kernel<<<EB, 256, 0, stream>>>(esrc, edst, cursor, csr_off, csr_w, dinv,
                                      E);

  // w1 = Ahat @ y (also s = Ahat @ 1) ; then fused final:
  // out = (leaky(Ahat @ w1 + s*u + v)) @ W_o2 + b_o2
  agg_kernel<1, 0><<<4096, 192, 0, stream>>>(
      yb, w1, offsets, csr_off, csr_w, dinv, svec, nullptr, nullptr, nullptr,
      nullptr, nullptr, nullptr, N);
  agg_kernel<0, 1><<<4096, 192, 0, stream>>>(
      w1, nullptr, offsets, csr_off, csr_w, dinv, nullptr, svec, uvec, vvec,
      W_o2, b_o2, out, N);
}